// Round 4
// baseline (4900.808 us; speedup 1.0000x reference)
//
#include <hip/hip_runtime.h>

// ---------------------------------------------------------------------------
// ERC GNN forward — round 4:
//  * two-phase bucketed edge scatter (kills random-store write amplification)
//  * mega-GEMM: 6 f_in GEMMs fused into one N=1536 launch; GAT L1 pair N=512;
//    3 GCN L1 GEMMs z-batched; f_self never materialized (att in epilogue)
//  * BN stats fused into agg kernels; BN norm fused into classifier
// ---------------------------------------------------------------------------

constexpr int D     = 256;
constexpr int NHEAD = 8;
constexpr int NCLS  = 7;
constexpr float BN_EPS = 1e-9f;

typedef short  s16x8 __attribute__((ext_vector_type(8)));
typedef float  f32x4 __attribute__((ext_vector_type(4)));

__device__ __forceinline__ unsigned short f2bf(float f) {
  unsigned int u = __builtin_bit_cast(unsigned int, f);
  u += 0x7FFFu + ((u >> 16) & 1u);          // round-to-nearest-even
  return (unsigned short)(u >> 16);
}
__device__ __forceinline__ float bf2f(unsigned short h) {
  unsigned int u = ((unsigned int)h) << 16;
  return __builtin_bit_cast(float, u);
}

__device__ __forceinline__ void gload_lds16(const void* g, void* l) {
  __builtin_amdgcn_global_load_lds(
      (const __attribute__((address_space(1))) unsigned int*)g,
      (__attribute__((address_space(3))) unsigned int*)l, 16, 0, 0);
}

struct Tri { const unsigned short* a0; const unsigned short* a1; const unsigned short* a2; };

// ---------------- unified bf16 MFMA GEMM ------------------------------------
// C_seg[M,256] = A[M,256] @ Wt_seg^T + bias_seg for each 256-col segment.
// attMode: cols 0..255 compute fused GAT attention only (no C store).
// z-batching (gridDim.z>1): per-z A (from Tri), Wt += z*65536, bias += z*256,
// Cbase += z*MD.
__launch_bounds__(256)
__global__ void k_gemm(Tri tri, const unsigned short* __restrict__ Wt,
                       const float* __restrict__ bias,
                       unsigned short* __restrict__ Cbase,
                       int M, int attMode, unsigned reluMask,
                       const float* __restrict__ a_s, const float* __restrict__ a_n,
                       float* __restrict__ attS, float* __restrict__ attN)
{
  __shared__ unsigned short As[128 * 32];
  __shared__ unsigned short Bs[128 * 32];
  const int z = blockIdx.z;
  const unsigned short* A = (z == 0) ? tri.a0 : ((z == 1) ? tri.a1 : tri.a2);
  Wt    += (size_t)z * D * D;
  bias  += (size_t)z * D;
  const size_t MD = (size_t)M * D;
  unsigned short* Cz = Cbase + (size_t)z * MD;

  const int t = threadIdx.x;
  const int wave = t >> 6, lane = t & 63;
  const int quad = lane >> 4, l16 = lane & 15;
  const int wm = (wave & 1) * 64, wn = (wave >> 1) * 64;
  const int bm = blockIdx.x * 128, bn = blockIdx.y * 128;
  const int seg = bn >> 8;                    // block lies fully in one segment
  const int att = attMode && (seg == 0);
  const int relu = (reluMask >> seg) & 1;

  f32x4 acc[4][4] = {};

  const int rA0 = wave * 32 + (lane >> 2);
  const int rA1 = rA0 + 16;
  const int sub = (lane & 3) * 8;
  const unsigned short* gA0 = A  + (size_t)min(bm + rA0, M - 1) * D + sub;
  const unsigned short* gA1 = A  + (size_t)min(bm + rA1, M - 1) * D + sub;
  const unsigned short* gB0 = Wt + (size_t)(bn + rA0) * D + sub;
  const unsigned short* gB1 = Wt + (size_t)(bn + rA1) * D + sub;
  unsigned short* lA0 = &As[wave * 1024];
  unsigned short* lA1 = &As[wave * 1024 + 512];
  unsigned short* lB0 = &Bs[wave * 1024];
  unsigned short* lB1 = &Bs[wave * 1024 + 512];

  for (int k0 = 0; k0 < D; k0 += 32) {
    gload_lds16(gA0 + k0, lA0);
    gload_lds16(gA1 + k0, lA1);
    gload_lds16(gB0 + k0, lB0);
    gload_lds16(gB1 + k0, lB1);
    __syncthreads();
    s16x8 af[4], bf[4];
#pragma unroll
    for (int mi = 0; mi < 4; ++mi)
      af[mi] = *(const s16x8*)(&As[(wm + mi * 16 + l16) * 32 + quad * 8]);
#pragma unroll
    for (int nj = 0; nj < 4; ++nj)
      bf[nj] = *(const s16x8*)(&Bs[(wn + nj * 16 + l16) * 32 + quad * 8]);
#pragma unroll
    for (int mi = 0; mi < 4; ++mi)
#pragma unroll
      for (int nj = 0; nj < 4; ++nj)
        acc[mi][nj] = __builtin_amdgcn_mfma_f32_16x16x32_bf16(af[mi], bf[nj], acc[mi][nj], 0, 0, 0);
    __syncthreads();
  }

  // C/D layout: col = l16, row = quad*4 + reg
  if (att) {
    // f_self used ONLY for attention -> no store. relu always applies.
    const int hb = (bn + wn) >> 5;
#pragma unroll
    for (int mi = 0; mi < 4; ++mi) {
#pragma unroll
      for (int h = 0; h < 2; ++h) {
        float ps[4] = {}, pn[4] = {};
#pragma unroll
        for (int j = 0; j < 2; ++j) {
          const int nj = h * 2 + j;
          const int col = bn + wn + nj * 16 + l16;
          const float bv = bias[col];
          const float av = a_s[col], nv = a_n[col];
#pragma unroll
          for (int r = 0; r < 4; ++r) {
            const float v = fmaxf(acc[mi][nj][r] + bv, 0.f);
            ps[r] = fmaf(v, av, ps[r]);
            pn[r] = fmaf(v, nv, pn[r]);
          }
        }
#pragma unroll
        for (int m = 1; m < 16; m <<= 1)
#pragma unroll
          for (int r = 0; r < 4; ++r) {
            ps[r] += __shfl_xor(ps[r], m);
            pn[r] += __shfl_xor(pn[r], m);
          }
        if (l16 == 0) {
#pragma unroll
          for (int r = 0; r < 4; ++r) {
            const int row = bm + wm + mi * 16 + quad * 4 + r;
            if (row < M) {
              const float s_ = ps[r], n_ = pn[r];
              attS[(size_t)row * NHEAD + hb + h] = (s_ > 0.f) ? s_ : 0.2f * s_;
              attN[(size_t)row * NHEAD + hb + h] = (n_ > 0.f) ? n_ : 0.2f * n_;
            }
          }
        }
      }
    }
  } else {
    unsigned short* C = Cz + (size_t)(seg - attMode) * MD;
#pragma unroll
    for (int nj = 0; nj < 4; ++nj) {
      const int col = bn + wn + nj * 16 + l16;
      const float bv = bias[col];
      const int cc = col & 255;
#pragma unroll
      for (int mi = 0; mi < 4; ++mi) {
#pragma unroll
        for (int r = 0; r < 4; ++r) {
          const int row = bm + wm + mi * 16 + quad * 4 + r;
          if (row < M) {
            float v = acc[mi][nj][r] + bv;
            if (relu) v = fmaxf(v, 0.f);
            C[(size_t)row * D + cc] = f2bf(v);
          }
        }
      }
    }
  }
}

// ---------------- conversions -----------------------------------------------
__global__ void k_cvt(const float* __restrict__ src, unsigned short* __restrict__ dst, int n8)
{
  const int i = blockIdx.x * 256 + threadIdx.x;
  if (i >= n8) return;
  const float4 a = *(const float4*)(src + (size_t)i * 8);
  const float4 b = *(const float4*)(src + (size_t)i * 8 + 4);
  uint4 o;
  o.x = (unsigned)f2bf(a.x) | ((unsigned)f2bf(a.y) << 16);
  o.y = (unsigned)f2bf(a.z) | ((unsigned)f2bf(a.w) << 16);
  o.z = (unsigned)f2bf(b.x) | ((unsigned)f2bf(b.y) << 16);
  o.w = (unsigned)f2bf(b.z) | ((unsigned)f2bf(b.w) << 16);
  *(uint4*)(dst + (size_t)i * 8) = o;
}

// mega-ordered weights: m 0:Ws0 1:Wn0 2:g0l0 3:g1l0 4:g2l0 5:self 6:Ws1 7:Wn1
//                        8:g0l1 9:g1l1 10:g2l1   -> Wt[m][col j][k d]
__global__ void k_cvt_w(const float* __restrict__ gat_Ws, const float* __restrict__ gat_Wn,
                        const float* __restrict__ gcn_W, const float* __restrict__ self_W,
                        unsigned short* __restrict__ Wt)
{
  const int m = blockIdx.x >> 8, j = blockIdx.x & 255, d = threadIdx.x;
  float v;
  if (m == 0 || m == 1 || m == 6 || m == 7) {
    const int l = (m >= 6) ? 1 : 0;
    const float* W = (m & 1) ? gat_Wn : gat_Ws;          // [L,H,D,DH]
    v = W[(((size_t)l * NHEAD + (j >> 5)) * D + d) * 32 + (j & 31)];
  } else if (m == 5) {
    v = self_W[(size_t)d * D + j];
  } else {
    const int g = (m < 5) ? (m - 2) : (m - 8);
    const int l = (m < 5) ? 0 : 1;
    v = gcn_W[(((size_t)g * 2 + l) * D + d) * D + j];    // [3,L,D,D]
  }
  Wt[((size_t)m * D + j) * D + d] = f2bf(v);
}

// bias2[m*256+j] in the same mega order
__global__ void k_cvt_b(const float* __restrict__ gat_bs, const float* __restrict__ gat_bn,
                        const float* __restrict__ gcn_b, const float* __restrict__ self_b,
                        float* __restrict__ bias2)
{
  const int m = blockIdx.x, j = threadIdx.x;
  float v;
  if (m == 0)       v = gat_bs[j];
  else if (m == 1)  v = gat_bn[j];
  else if (m == 5)  v = self_b[j];
  else if (m == 6)  v = gat_bs[D + j];
  else if (m == 7)  v = gat_bn[D + j];
  else {
    const int g = (m < 5) ? (m - 2) : (m - 8);
    const int l = (m < 5) ? 0 : 1;
    v = gcn_b[((size_t)g * 2 + l) * D + j];
  }
  bias2[(size_t)m * D + j] = v;
}

// ---------------- batched CSR build (4 adjacencies) --------------------------
__global__ void k_count(const int* __restrict__ rows, int* __restrict__ cnt, int E4, int E, int N)
{
  const int i = blockIdx.x * 256 + threadIdx.x;
  if (i < E4) atomicAdd(&cnt[(i / E) * N + rows[i]], 1);
}

__global__ void k_scan_blk(const int* __restrict__ in, int* __restrict__ scanTmp,
                           int* __restrict__ blkSum, int n)
{
  __shared__ int buf[256];
  const int t = threadIdx.x, i = blockIdx.x * 256 + t;
  const int v = (i < n) ? in[i] : 0;
  buf[t] = v; __syncthreads();
  for (int off = 1; off < 256; off <<= 1) {
    const int x = (t >= off) ? buf[t - off] : 0;
    __syncthreads();
    buf[t] += x; __syncthreads();
  }
  if (i < n) scanTmp[i] = buf[t];
  if (t == 255) blkSum[blockIdx.x] = buf[255];
}

__global__ void k_scan_top(int* __restrict__ blkSum, int G)
{
  __shared__ int buf[1024];
  const int t = threadIdx.x;
  const int v = (t < G) ? blkSum[t] : 0;
  buf[t] = v; __syncthreads();
  for (int off = 1; off < 1024; off <<= 1) {
    const int x = (t >= off) ? buf[t - off] : 0;
    __syncthreads();
    buf[t] += x; __syncthreads();
  }
  if (t < G) blkSum[t] = buf[t] - v;
}

__global__ void k_scan_fin(const int* __restrict__ scanTmp, const int* __restrict__ blkOff,
                           int* __restrict__ rowptr, int n)
{
  const int i = blockIdx.x * 256 + threadIdx.x;
  if (i < n) rowptr[i + 1] = scanTmp[i] + blkOff[blockIdx.x];
  if (i == 0) rowptr[0] = 0;
}

// Phase A: scatter into 128-node buckets (cursor locality -> ~1x write amp).
// tmp record: { (local_row<<17)|col , val_bits }
__global__ void k_phaseA(const int* __restrict__ rows, const int* __restrict__ cols,
                         const float* __restrict__ vals,
                         const int* __restrict__ rowptr, int* __restrict__ bfill,
                         int2* __restrict__ tmp, int E4, int E, int N)
{
  const int i = blockIdx.x * 256 + threadIdx.x;
  if (i >= E4) return;
  const int g = (i / E) * N + rows[i];
  const int b = g >> 7;
  const int p = rowptr[b << 7] + atomicAdd(&bfill[b], 1);
  tmp[p] = make_int2(((g & 127) << 17) | cols[i], __float_as_int(vals[i]));
}

// Phase B: one block per bucket; LDS cursors -> final CSR order (8KB window).
__global__ void k_phaseB(const int2* __restrict__ tmp, const int* __restrict__ rowptr,
                         int2* __restrict__ edge, int N4)
{
  __shared__ int lf[128];
  const int b = blockIdx.x, t = threadIdx.x;
  const int gs = b << 7;
  const int ge = min(gs + 128, N4);
  if (t < ge - gs) lf[t] = rowptr[gs + t];
  __syncthreads();
  const int s = rowptr[gs], e = rowptr[ge];
  for (int i = s + t; i < e; i += 256) {
    const int2 rec = tmp[i];
    const int lr = (rec.x >> 17) & 127;
    const int p = atomicAdd(&lf[lr], 1);
    edge[p] = make_int2(rec.x & 0x1FFFF, rec.y);
  }
}

// ---------------- Aggregations (fused BN stats) -----------------------------
__device__ __forceinline__ void acc8(float* a, uint4 f, float c) {
  const unsigned w[4] = {f.x, f.y, f.z, f.w};
#pragma unroll
  for (int k = 0; k < 4; ++k) {
    a[2 * k]     = fmaf(c, bf2f((unsigned short)(w[k] & 0xffff)), a[2 * k]);
    a[2 * k + 1] = fmaf(c, bf2f((unsigned short)(w[k] >> 16)),    a[2 * k + 1]);
  }
}

__device__ __forceinline__ uint4 pack8(const float* a) {
  unsigned ov[4];
#pragma unroll
  for (int k = 0; k < 4; ++k)
    ov[k] = (unsigned)f2bf(a[2 * k]) | ((unsigned)f2bf(a[2 * k + 1]) << 16);
  uint4 o; o.x = ov[0]; o.y = ov[1]; o.z = ov[2]; o.w = ov[3];
  return o;
}

__device__ __forceinline__ void stats_epilogue(float* s8, float* q8, float* sums)
{
  __shared__ float ls[256][8];
  __shared__ float lq[256][8];
  const int t = threadIdx.x, cg = t & 31, rg = t >> 5;
#pragma unroll
  for (int k = 0; k < 8; ++k) { ls[t][k] = s8[k]; lq[t][k] = q8[k]; }
  __syncthreads();
  if (rg == 0) {
#pragma unroll
    for (int g = 1; g < 8; ++g)
#pragma unroll
      for (int k = 0; k < 8; ++k) { s8[k] += ls[cg + 32 * g][k]; q8[k] += lq[cg + 32 * g][k]; }
#pragma unroll
    for (int k = 0; k < 8; ++k) {
      atomicAdd(&sums[cg * 8 + k], s8[k]);
      atomicAdd(&sums[D + cg * 8 + k], q8[k]);
    }
  }
}

__launch_bounds__(256)
__global__ void k_gat_agg(const unsigned short* __restrict__ fneigh,
                          const float* __restrict__ attS, const float* __restrict__ attN,
                          const int* __restrict__ rowptr, const int2* __restrict__ edge,
                          unsigned short* __restrict__ out, float* __restrict__ sums, int N)
{
  const int warp = threadIdx.x >> 5, lane = threadIdx.x & 31;
  const int head = lane >> 2;
  float s8[8] = {}, q8[8] = {};
  for (int n = blockIdx.x * 8 + warp; n < N; n += gridDim.x * 8) {
    const float as = attS[(size_t)n * NHEAD + head];
    float a[8] = {};
    int p = rowptr[n];
    const int e = rowptr[n + 1];
    for (; p + 1 < e; p += 2) {
      const int2 e0 = edge[p], e1 = edge[p + 1];
      const float c0 = (as + attN[(size_t)e0.x * NHEAD + head]) * __int_as_float(e0.y);
      const float c1 = (as + attN[(size_t)e1.x * NHEAD + head]) * __int_as_float(e1.y);
      const uint4 f0 = *(const uint4*)(fneigh + (size_t)e0.x * D + lane * 8);
      const uint4 f1 = *(const uint4*)(fneigh + (size_t)e1.x * D + lane * 8);
      acc8(a, f0, c0);
      acc8(a, f1, c1);
    }
    if (p < e) {
      const int2 e0 = edge[p];
      const float c0 = (as + attN[(size_t)e0.x * NHEAD + head]) * __int_as_float(e0.y);
      const uint4 f0 = *(const uint4*)(fneigh + (size_t)e0.x * D + lane * 8);
      acc8(a, f0, c0);
    }
    *(uint4*)(out + (size_t)n * D + lane * 8) = pack8(a);
#pragma unroll
    for (int k = 0; k < 8; ++k) { s8[k] += a[k]; q8[k] = fmaf(a[k], a[k], q8[k]); }
  }
  stats_epilogue(s8, q8, sums);
}

__launch_bounds__(256)
__global__ void k_gcn_agg(const unsigned short* __restrict__ Hm,
                          const int* __restrict__ rowptr, const int2* __restrict__ edge,
                          unsigned short* __restrict__ out, float* __restrict__ sums, int N)
{
  const int warp = threadIdx.x >> 5, lane = threadIdx.x & 31;
  float s8[8] = {}, q8[8] = {};
  for (int n = blockIdx.x * 8 + warp; n < N; n += gridDim.x * 8) {
    float a[8] = {};
    int p = rowptr[n];
    const int e = rowptr[n + 1];
    for (; p + 1 < e; p += 2) {
      const int2 e0 = edge[p], e1 = edge[p + 1];
      const uint4 f0 = *(const uint4*)(Hm + (size_t)e0.x * D + lane * 8);
      const uint4 f1 = *(const uint4*)(Hm + (size_t)e1.x * D + lane * 8);
      acc8(a, f0, __int_as_float(e0.y));
      acc8(a, f1, __int_as_float(e1.y));
    }
    if (p < e) {
      const int2 e0 = edge[p];
      const uint4 f0 = *(const uint4*)(Hm + (size_t)e0.x * D + lane * 8);
      acc8(a, f0, __int_as_float(e0.y));
    }
#pragma unroll
    for (int k = 0; k < 8; ++k) {             // relu before BN
      a[k] = fmaxf(a[k], 0.f);
      s8[k] += a[k]; q8[k] = fmaf(a[k], a[k], q8[k]);
    }
    *(uint4*)(out + (size_t)n * D + lane * 8) = pack8(a);
  }
  stats_epilogue(s8, q8, sums);
}

// ---------------- BatchNorm (standalone pieces) -----------------------------
__launch_bounds__(256)
__global__ void k_bn_stats(const unsigned short* __restrict__ X, float* __restrict__ sums, int M)
{
  const int t = threadIdx.x, cg = t & 31, rg = t >> 5;
  float s[8] = {}, q[8] = {};
  for (int r = blockIdx.x * 8 + rg; r < M; r += gridDim.x * 8) {
    const uint4 f = *(const uint4*)(X + (size_t)r * D + cg * 8);
    const unsigned w[4] = {f.x, f.y, f.z, f.w};
#pragma unroll
    for (int k = 0; k < 4; ++k) {
      const float lo = bf2f((unsigned short)(w[k] & 0xffff));
      const float hi = bf2f((unsigned short)(w[k] >> 16));
      s[2 * k]     += lo; q[2 * k]     = fmaf(lo, lo, q[2 * k]);
      s[2 * k + 1] += hi; q[2 * k + 1] = fmaf(hi, hi, q[2 * k + 1]);
    }
  }
  stats_epilogue(s, q, sums);
}

__global__ void k_bn_norm(unsigned short* __restrict__ X, const float* __restrict__ sums, int M)
{
  __shared__ float mu[D], rs[D];
  const int t = threadIdx.x;
  {
    const float m_ = sums[t] / (float)M;
    const float v_ = sums[D + t] / (float)M - m_ * m_;
    mu[t] = m_;
    rs[t] = rsqrtf(v_ + BN_EPS);
  }
  __syncthreads();
  const size_t idx = (size_t)blockIdx.x * 256 + t;   // unit = 8 elems
  const int j0 = (int)((idx * 8) & (D - 1));
  uint4 raw = *(uint4*)(X + idx * 8);
  unsigned int w[4] = {raw.x, raw.y, raw.z, raw.w};
  unsigned int ov[4];
#pragma unroll
  for (int k = 0; k < 4; ++k) {
    const float lo = (bf2f((unsigned short)(w[k] & 0xffff)) - mu[j0 + 2 * k])     * rs[j0 + 2 * k];
    const float hi = (bf2f((unsigned short)(w[k] >> 16))    - mu[j0 + 2 * k + 1]) * rs[j0 + 2 * k + 1];
    ov[k] = (unsigned)f2bf(lo) | ((unsigned)f2bf(hi) << 16);
  }
  uint4 o; o.x = ov[0]; o.y = ov[1]; o.z = ov[2]; o.w = ov[3];
  *(uint4*)(X + idx * 8) = o;
}

// ---------------- Classifier (fused BN norm) --------------------------------
__global__ void k_classifier(const unsigned short* __restrict__ F, const float* __restrict__ W,
                             const float* __restrict__ sums, const float* __restrict__ cls_b,
                             float* __restrict__ out, int N, int baseRow, int writeMode)
{
  const int n = blockIdx.x * 8 + (threadIdx.x >> 5);
  if (n >= N) return;
  const int lane = threadIdx.x & 31;
  const int j0 = lane * 8;
  float mu[8], rs[8];
#pragma unroll
  for (int k = 0; k < 8; ++k) {
    const float m_ = sums[j0 + k] / (float)N;
    const float v_ = sums[D + j0 + k] / (float)N - m_ * m_;
    mu[k] = m_;
    rs[k] = rsqrtf(v_ + BN_EPS);
  }
  const uint4 f = *(const uint4*)(F + (size_t)n * D + j0);
  const unsigned w[4] = {f.x, f.y, f.z, f.w};
  float fv[8];
#pragma unroll
  for (int k = 0; k < 4; ++k) {
    fv[2 * k]     = (bf2f((unsigned short)(w[k] & 0xffff)) - mu[2 * k])     * rs[2 * k];
    fv[2 * k + 1] = (bf2f((unsigned short)(w[k] >> 16))    - mu[2 * k + 1]) * rs[2 * k + 1];
  }
  const float* Wr = W + (size_t)(baseRow + j0) * NCLS;
  float p[NCLS];
#pragma unroll
  for (int c = 0; c < NCLS; ++c) {
    float s = 0.f;
#pragma unroll
    for (int k = 0; k < 8; ++k) s = fmaf(fv[k], Wr[k * NCLS + c], s);
    p[c] = s;
  }
#pragma unroll
  for (int m = 1; m < 32; m <<= 1)
#pragma unroll
    for (int c = 0; c < NCLS; ++c) p[c] += __shfl_xor(p[c], m);
  if (lane == 0) {
    float* o = out + (size_t)n * NCLS;
    if (writeMode) {
#pragma unroll
      for (int c = 0; c < NCLS; ++c) o[c] = cls_b[c] + p[c];
    } else {
#pragma unroll
      for (int c = 0; c < NCLS; ++c) o[c] += p[c];
    }
  }
}

// ---------------------------------------------------------------------------
extern "C" void kernel_launch(void* const* d_in, const int* in_sizes, int n_in,
                              void* d_out, int out_size, void* d_ws, size_t ws_size,
                              hipStream_t stream)
{
  const float* f_in   = (const float*)d_in[0];
  const int*   erow   = (const int*)d_in[1];
  const int*   ecol   = (const int*)d_in[2];
  const float* eval   = (const float*)d_in[3];
  const float* gat_Ws = (const float*)d_in[4];
  const float* gat_bs = (const float*)d_in[5];
  const float* gat_Wn = (const float*)d_in[6];
  const float* gat_bn = (const float*)d_in[7];
  const float* gat_as = (const float*)d_in[8];
  const float* gat_an = (const float*)d_in[9];
  const float* gcn_W  = (const float*)d_in[10];
  const float* gcn_b  = (const float*)d_in[11];
  const float* self_W = (const float*)d_in[12];
  const float* self_b = (const float*)d_in[13];
  const float* cls_W  = (const float*)d_in[14];
  const float* cls_b  = (const float*)d_in[15];
  float* out = (float*)d_out;

  const int N  = in_sizes[0] / D;      // 50000
  const int E  = in_sizes[1] / 4;      // 400000
  const int E4 = 4 * E, N4 = 4 * N;
  const size_t ND = (size_t)N * D;
  const size_t WM = (size_t)D * D;

  // ---- workspace carve-up ----
  unsigned short* F  = (unsigned short*)d_ws;    // also GCN X0
  unsigned short* O0 = F + ND;                   // O0..O4 contiguous (GEMM slots)
  unsigned short* O1 = O0 + ND;
  unsigned short* O2 = O0 + 2 * ND;
  unsigned short* O3 = O0 + 3 * ND;
  unsigned short* O4 = O0 + 4 * ND;              // self out; Phase-A tmp aliases here
  float* attS   = (float*)(O0 + 5 * ND);
  float* attN   = attS + (size_t)N * NHEAD;
  unsigned short* Wt = (unsigned short*)(attN + (size_t)N * NHEAD);   // 11*65536
  float* bias2  = (float*)(Wt + 11 * WM);        // 11*256
  int*   blkSum = (int*)(bias2 + 11 * D);        // 1024
  int*   rowptr = blkSum + 1024;                 // N4+1 (+pad)
  int2*  edge   = (int2*)(rowptr + N4 + 4);      // E4 (final CSR records)
  float* bnsums = (float*)(edge + E4);           // 9*512  [zeroed]
  // aliases into the edge region (all dead before Phase B writes edge):
  int*   cnt     = (int*)edge;                   // N4     [zeroed]
  int*   bfill   = cnt + N4;                     // 1600   [zeroed]
  int*   scanTmp = bfill + 1600;                 // N4
  int2*  tmp     = (int2*)O4;                    // E4 (dead before GEMM1 writes O4)

  const int nb8     = (N + 7) / 8;
  const int scanG   = (N4 + 255) / 256;
  const int buckets = (N4 + 127) >> 7;
  const int aggG    = 2048;

  hipMemsetAsync(cnt, 0, ((size_t)N4 + 1600) * sizeof(int), stream);
  hipMemsetAsync(bnsums, 0, 9 * 2 * D * sizeof(float), stream);

  // conversions
  k_cvt  <<<(int)(ND / 8 + 255) / 256, 256, 0, stream>>>(f_in, F, (int)(ND / 8));
  k_cvt_w<<<11 * 256, 256, 0, stream>>>(gat_Ws, gat_Wn, gcn_W, self_W, Wt);
  k_cvt_b<<<11, 256, 0, stream>>>(gat_bs, gat_bn, gcn_b, self_b, bias2);

  // batched CSR (4 adjacencies) with bucketed two-phase scatter
  k_count   <<<(E4 + 255) / 256, 256, 0, stream>>>(erow, cnt, E4, E, N);
  k_scan_blk<<<scanG, 256, 0, stream>>>(cnt, scanTmp, blkSum, N4);
  k_scan_top<<<1, 1024, 0, stream>>>(blkSum, scanG);
  k_scan_fin<<<scanG, 256, 0, stream>>>(scanTmp, blkSum, rowptr, N4);
  k_phaseA  <<<(E4 + 255) / 256, 256, 0, stream>>>(erow, ecol, eval, rowptr, bfill,
                                                   tmp, E4, E, N);
  k_phaseB  <<<buckets, 256, 0, stream>>>(tmp, rowptr, edge, N4);

  const int* rp0 = rowptr;
  const int* rp1 = rowptr + N;
  const int* rp2 = rowptr + 2 * N;
  const int* rp3 = rowptr + 3 * N;
  float* sums = bnsums;   // slot i at sums + i*512

  Tri triF  = {F, F, F};
  Tri triX  = {F, O0, O4};

  // ---- mega GEMM 1: A=F(f_in), cols [att | Wn0 | g0 | g1 | g2 | self] ------
  k_gemm<<<dim3((N + 127) / 128, 6 * 2, 1), 256, 0, stream>>>(
      triF, Wt, bias2, O0, N, 1, 0x22u, gat_as, gat_an, attS, attN);

  // ---- self branch (frees O4 early) ---------------------------------------
  k_bn_stats  <<<128, 256, 0, stream>>>(O4, sums + 8 * 512, N);
  k_classifier<<<nb8, 256, 0, stream>>>(O4, cls_W, sums + 8 * 512, cls_b, out, N, 4 * D, 1);

  // ---- GAT branch ----------------------------------------------------------
  k_gat_agg<<<aggG, 256, 0, stream>>>(O0, attS, attN, rp0, edge, F, sums + 0 * 512, N);
  k_bn_norm<<<(int)(ND / 8 / 256), 256, 0, stream>>>(F, sums + 0 * 512, N);
  k_gemm<<<dim3((N + 127) / 128, 4, 1), 256, 0, stream>>>(
      triF, Wt + 6 * WM, bias2 + 6 * D, O0, N, 1, 0x02u,
      gat_as + D, gat_an + D, attS, attN);
  k_gat_agg<<<aggG, 256, 0, stream>>>(O0, attS, attN, rp0, edge, F, sums + 1 * 512, N);
  k_classifier<<<nb8, 256, 0, stream>>>(F, cls_W, sums + 1 * 512, cls_b, out, N, 0, 0);

  // ---- 3 GCN branches ------------------------------------------------------
  k_gcn_agg<<<aggG, 256, 0, stream>>>(O1, rp1, edge, F,  sums + 2 * 512, N);
  k_gcn_agg<<<aggG, 256, 0, stream>>>(O2, rp2, edge, O0, sums + 4 * 512, N);
  k_gcn_agg<<<aggG, 256, 0, stream>>>(O3, rp3, edge, O4, sums + 6 * 512, N);
  k_bn_norm<<<(int)(ND / 8 / 256), 256, 0, stream>>>(F,  sums + 2 * 512, N);
  k_bn_norm<<<(int)(ND / 8 / 256), 256, 0, stream>>>(O0, sums + 4 * 512, N);
  k_bn_norm<<<(int)(ND / 8 / 256), 256, 0, stream>>>(O4, sums + 6 * 512, N);
  k_gemm<<<dim3((N + 127) / 128, 2, 3), 256, 0, stream>>>(
      triX, Wt + 8 * WM, bias2 + 8 * D, O1, N, 0, 0x0u,
      nullptr, nullptr, nullptr, nullptr);
  k_gcn_agg<<<aggG, 256, 0, stream>>>(O1, rp1, edge, F,  sums + 3 * 512, N);
  k_gcn_agg<<<aggG, 256, 0, stream>>>(O2, rp2, edge, O0, sums + 5 * 512, N);
  k_gcn_agg<<<aggG, 256, 0, stream>>>(O3, rp3, edge, O4, sums + 7 * 512, N);
  k_classifier<<<nb8, 256, 0, stream>>>(F,  cls_W, sums + 3 * 512, cls_b, out, N, 1 * D, 0);
  k_classifier<<<nb8, 256, 0, stream>>>(O0, cls_W, sums + 5 * 512, cls_b, out, N, 2 * D, 0);
  k_classifier<<<nb8, 256, 0, stream>>>(O4, cls_W, sums + 7 * 512, cls_b, out, N, 3 * D, 0);
}

// Round 5
// 1923.791 us; speedup vs baseline: 2.5475x; 2.5475x over previous
//
#include <hip/hip_runtime.h>

// ---------------------------------------------------------------------------
// ERC GNN forward — round 5:
//  r4 structure (two-phase bucketed scatter, mega-GEMM, classifier-fused norm)
//  with the agg kernels reverted to r3 one-shot form. r4's BN-stats fusion into
//  the agg loop spilled to scratch (WRITE 57.8MB vs 25.6MB payload, VGPR=32)
//  and cost 6x on every agg — stats are standalone passes again.
// ---------------------------------------------------------------------------

constexpr int D     = 256;
constexpr int NHEAD = 8;
constexpr int NCLS  = 7;
constexpr float BN_EPS = 1e-9f;

typedef short  s16x8 __attribute__((ext_vector_type(8)));
typedef float  f32x4 __attribute__((ext_vector_type(4)));

__device__ __forceinline__ unsigned short f2bf(float f) {
  unsigned int u = __builtin_bit_cast(unsigned int, f);
  u += 0x7FFFu + ((u >> 16) & 1u);          // round-to-nearest-even
  return (unsigned short)(u >> 16);
}
__device__ __forceinline__ float bf2f(unsigned short h) {
  unsigned int u = ((unsigned int)h) << 16;
  return __builtin_bit_cast(float, u);
}

__device__ __forceinline__ void gload_lds16(const void* g, void* l) {
  __builtin_amdgcn_global_load_lds(
      (const __attribute__((address_space(1))) unsigned int*)g,
      (__attribute__((address_space(3))) unsigned int*)l, 16, 0, 0);
}

struct Tri { const unsigned short* a0; const unsigned short* a1; const unsigned short* a2; };

// ---------------- unified bf16 MFMA GEMM ------------------------------------
// C_seg[M,256] = A[M,256] @ Wt_seg^T + bias_seg per 256-col segment.
// attMode: segment 0 computes fused GAT attention only (no C store).
// z-batching: per-z A (Tri), Wt += z*65536, bias += z*256, Cbase += z*MD.
__launch_bounds__(256)
__global__ void k_gemm(Tri tri, const unsigned short* __restrict__ Wt,
                       const float* __restrict__ bias,
                       unsigned short* __restrict__ Cbase,
                       int M, int attMode, unsigned reluMask,
                       const float* __restrict__ a_s, const float* __restrict__ a_n,
                       float* __restrict__ attS, float* __restrict__ attN)
{
  __shared__ unsigned short As[128 * 32];
  __shared__ unsigned short Bs[128 * 32];
  const int z = blockIdx.z;
  const unsigned short* A = (z == 0) ? tri.a0 : ((z == 1) ? tri.a1 : tri.a2);
  Wt    += (size_t)z * D * D;
  bias  += (size_t)z * D;
  const size_t MD = (size_t)M * D;
  unsigned short* Cz = Cbase + (size_t)z * MD;

  const int t = threadIdx.x;
  const int wave = t >> 6, lane = t & 63;
  const int quad = lane >> 4, l16 = lane & 15;
  const int wm = (wave & 1) * 64, wn = (wave >> 1) * 64;
  const int bm = blockIdx.x * 128, bn = blockIdx.y * 128;
  const int seg = bn >> 8;                    // block lies fully in one segment
  const int att = attMode && (seg == 0);
  const int relu = (reluMask >> seg) & 1;

  f32x4 acc[4][4] = {};

  const int rA0 = wave * 32 + (lane >> 2);
  const int rA1 = rA0 + 16;
  const int sub = (lane & 3) * 8;
  const unsigned short* gA0 = A  + (size_t)min(bm + rA0, M - 1) * D + sub;
  const unsigned short* gA1 = A  + (size_t)min(bm + rA1, M - 1) * D + sub;
  const unsigned short* gB0 = Wt + (size_t)(bn + rA0) * D + sub;
  const unsigned short* gB1 = Wt + (size_t)(bn + rA1) * D + sub;
  unsigned short* lA0 = &As[wave * 1024];
  unsigned short* lA1 = &As[wave * 1024 + 512];
  unsigned short* lB0 = &Bs[wave * 1024];
  unsigned short* lB1 = &Bs[wave * 1024 + 512];

  for (int k0 = 0; k0 < D; k0 += 32) {
    gload_lds16(gA0 + k0, lA0);
    gload_lds16(gA1 + k0, lA1);
    gload_lds16(gB0 + k0, lB0);
    gload_lds16(gB1 + k0, lB1);
    __syncthreads();
    s16x8 af[4], bf[4];
#pragma unroll
    for (int mi = 0; mi < 4; ++mi)
      af[mi] = *(const s16x8*)(&As[(wm + mi * 16 + l16) * 32 + quad * 8]);
#pragma unroll
    for (int nj = 0; nj < 4; ++nj)
      bf[nj] = *(const s16x8*)(&Bs[(wn + nj * 16 + l16) * 32 + quad * 8]);
#pragma unroll
    for (int mi = 0; mi < 4; ++mi)
#pragma unroll
      for (int nj = 0; nj < 4; ++nj)
        acc[mi][nj] = __builtin_amdgcn_mfma_f32_16x16x32_bf16(af[mi], bf[nj], acc[mi][nj], 0, 0, 0);
    __syncthreads();
  }

  // C/D layout: col = l16, row = quad*4 + reg
  if (att) {
    // f_self used ONLY for attention -> no store. relu always applies.
    const int hb = (bn + wn) >> 5;
#pragma unroll
    for (int mi = 0; mi < 4; ++mi) {
#pragma unroll
      for (int h = 0; h < 2; ++h) {
        float ps[4] = {}, pn[4] = {};
#pragma unroll
        for (int j = 0; j < 2; ++j) {
          const int nj = h * 2 + j;
          const int col = bn + wn + nj * 16 + l16;
          const float bv = bias[col];
          const float av = a_s[col], nv = a_n[col];
#pragma unroll
          for (int r = 0; r < 4; ++r) {
            const float v = fmaxf(acc[mi][nj][r] + bv, 0.f);
            ps[r] = fmaf(v, av, ps[r]);
            pn[r] = fmaf(v, nv, pn[r]);
          }
        }
#pragma unroll
        for (int m = 1; m < 16; m <<= 1)
#pragma unroll
          for (int r = 0; r < 4; ++r) {
            ps[r] += __shfl_xor(ps[r], m);
            pn[r] += __shfl_xor(pn[r], m);
          }
        if (l16 == 0) {
#pragma unroll
          for (int r = 0; r < 4; ++r) {
            const int row = bm + wm + mi * 16 + quad * 4 + r;
            if (row < M) {
              const float s_ = ps[r], n_ = pn[r];
              attS[(size_t)row * NHEAD + hb + h] = (s_ > 0.f) ? s_ : 0.2f * s_;
              attN[(size_t)row * NHEAD + hb + h] = (n_ > 0.f) ? n_ : 0.2f * n_;
            }
          }
        }
      }
    }
  } else {
    unsigned short* C = Cz + (size_t)(seg - attMode) * MD;
#pragma unroll
    for (int nj = 0; nj < 4; ++nj) {
      const int col = bn + wn + nj * 16 + l16;
      const float bv = bias[col];
      const int cc = col & 255;
#pragma unroll
      for (int mi = 0; mi < 4; ++mi) {
#pragma unroll
        for (int r = 0; r < 4; ++r) {
          const int row = bm + wm + mi * 16 + quad * 4 + r;
          if (row < M) {
            float v = acc[mi][nj][r] + bv;
            if (relu) v = fmaxf(v, 0.f);
            C[(size_t)row * D + cc] = f2bf(v);
          }
        }
      }
    }
  }
}

// ---------------- conversions -----------------------------------------------
__global__ void k_cvt(const float* __restrict__ src, unsigned short* __restrict__ dst, int n8)
{
  const int i = blockIdx.x * 256 + threadIdx.x;
  if (i >= n8) return;
  const float4 a = *(const float4*)(src + (size_t)i * 8);
  const float4 b = *(const float4*)(src + (size_t)i * 8 + 4);
  uint4 o;
  o.x = (unsigned)f2bf(a.x) | ((unsigned)f2bf(a.y) << 16);
  o.y = (unsigned)f2bf(a.z) | ((unsigned)f2bf(a.w) << 16);
  o.z = (unsigned)f2bf(b.x) | ((unsigned)f2bf(b.y) << 16);
  o.w = (unsigned)f2bf(b.z) | ((unsigned)f2bf(b.w) << 16);
  *(uint4*)(dst + (size_t)i * 8) = o;
}

// mega-ordered weights: m 0:Ws0 1:Wn0 2:g0l0 3:g1l0 4:g2l0 5:self 6:Ws1 7:Wn1
//                        8:g0l1 9:g1l1 10:g2l1   -> Wt[m][col j][k d]
__global__ void k_cvt_w(const float* __restrict__ gat_Ws, const float* __restrict__ gat_Wn,
                        const float* __restrict__ gcn_W, const float* __restrict__ self_W,
                        unsigned short* __restrict__ Wt)
{
  const int m = blockIdx.x >> 8, j = blockIdx.x & 255, d = threadIdx.x;
  float v;
  if (m == 0 || m == 1 || m == 6 || m == 7) {
    const int l = (m >= 6) ? 1 : 0;
    const float* W = (m & 1) ? gat_Wn : gat_Ws;          // [L,H,D,DH]
    v = W[(((size_t)l * NHEAD + (j >> 5)) * D + d) * 32 + (j & 31)];
  } else if (m == 5) {
    v = self_W[(size_t)d * D + j];
  } else {
    const int g = (m < 5) ? (m - 2) : (m - 8);
    const int l = (m < 5) ? 0 : 1;
    v = gcn_W[(((size_t)g * 2 + l) * D + d) * D + j];    // [3,L,D,D]
  }
  Wt[((size_t)m * D + j) * D + d] = f2bf(v);
}

// bias2[m*256+j] in the same mega order
__global__ void k_cvt_b(const float* __restrict__ gat_bs, const float* __restrict__ gat_bn,
                        const float* __restrict__ gcn_b, const float* __restrict__ self_b,
                        float* __restrict__ bias2)
{
  const int m = blockIdx.x, j = threadIdx.x;
  float v;
  if (m == 0)       v = gat_bs[j];
  else if (m == 1)  v = gat_bn[j];
  else if (m == 5)  v = self_b[j];
  else if (m == 6)  v = gat_bs[D + j];
  else if (m == 7)  v = gat_bn[D + j];
  else {
    const int g = (m < 5) ? (m - 2) : (m - 8);
    const int l = (m < 5) ? 0 : 1;
    v = gcn_b[((size_t)g * 2 + l) * D + j];
  }
  bias2[(size_t)m * D + j] = v;
}

// ---------------- batched CSR build (4 adjacencies) --------------------------
__global__ void k_count(const int* __restrict__ rows, int* __restrict__ cnt, int E4, int E, int N)
{
  const int i = blockIdx.x * 256 + threadIdx.x;
  if (i < E4) atomicAdd(&cnt[(i / E) * N + rows[i]], 1);
}

__global__ void k_scan_blk(const int* __restrict__ in, int* __restrict__ scanTmp,
                           int* __restrict__ blkSum, int n)
{
  __shared__ int buf[256];
  const int t = threadIdx.x, i = blockIdx.x * 256 + t;
  const int v = (i < n) ? in[i] : 0;
  buf[t] = v; __syncthreads();
  for (int off = 1; off < 256; off <<= 1) {
    const int x = (t >= off) ? buf[t - off] : 0;
    __syncthreads();
    buf[t] += x; __syncthreads();
  }
  if (i < n) scanTmp[i] = buf[t];
  if (t == 255) blkSum[blockIdx.x] = buf[255];
}

__global__ void k_scan_top(int* __restrict__ blkSum, int G)
{
  __shared__ int buf[1024];
  const int t = threadIdx.x;
  const int v = (t < G) ? blkSum[t] : 0;
  buf[t] = v; __syncthreads();
  for (int off = 1; off < 1024; off <<= 1) {
    const int x = (t >= off) ? buf[t - off] : 0;
    __syncthreads();
    buf[t] += x; __syncthreads();
  }
  if (t < G) blkSum[t] = buf[t] - v;
}

__global__ void k_scan_fin(const int* __restrict__ scanTmp, const int* __restrict__ blkOff,
                           int* __restrict__ rowptr, int n)
{
  const int i = blockIdx.x * 256 + threadIdx.x;
  if (i < n) rowptr[i + 1] = scanTmp[i] + blkOff[blockIdx.x];
  if (i == 0) rowptr[0] = 0;
}

// Phase A: scatter into 128-node buckets (cursor locality -> ~1x write amp).
// tmp record: { (local_row<<17)|col , val_bits }
__global__ void k_phaseA(const int* __restrict__ rows, const int* __restrict__ cols,
                         const float* __restrict__ vals,
                         const int* __restrict__ rowptr, int* __restrict__ bfill,
                         int2* __restrict__ tmp, int E4, int E, int N)
{
  const int i = blockIdx.x * 256 + threadIdx.x;
  if (i >= E4) return;
  const int g = (i / E) * N + rows[i];
  const int b = g >> 7;
  const int p = rowptr[b << 7] + atomicAdd(&bfill[b], 1);
  tmp[p] = make_int2(((g & 127) << 17) | cols[i], __float_as_int(vals[i]));
}

// Phase B: one block per bucket; LDS cursors -> final CSR order (8KB window).
__global__ void k_phaseB(const int2* __restrict__ tmp, const int* __restrict__ rowptr,
                         int2* __restrict__ edge, int N4)
{
  __shared__ int lf[128];
  const int b = blockIdx.x, t = threadIdx.x;
  const int gs = b << 7;
  const int ge = min(gs + 128, N4);
  if (t < ge - gs) lf[t] = rowptr[gs + t];
  __syncthreads();
  const int s = rowptr[gs], e = rowptr[ge];
  for (int i = s + t; i < e; i += 256) {
    const int2 rec = tmp[i];
    const int lr = (rec.x >> 17) & 127;
    const int p = atomicAdd(&lf[lr], 1);
    edge[p] = make_int2(rec.x & 0x1FFFF, rec.y);
  }
}

// ---------------- Aggregations (one-shot, r3 form — no fused stats) ---------
__device__ __forceinline__ void acc8(float* a, uint4 f, float c) {
  const unsigned w[4] = {f.x, f.y, f.z, f.w};
#pragma unroll
  for (int k = 0; k < 4; ++k) {
    a[2 * k]     = fmaf(c, bf2f((unsigned short)(w[k] & 0xffff)), a[2 * k]);
    a[2 * k + 1] = fmaf(c, bf2f((unsigned short)(w[k] >> 16)),    a[2 * k + 1]);
  }
}

__device__ __forceinline__ uint4 pack8(const float* a, bool relu) {
  unsigned ov[4];
#pragma unroll
  for (int k = 0; k < 4; ++k) {
    float lo = a[2 * k], hi = a[2 * k + 1];
    if (relu) { lo = fmaxf(lo, 0.f); hi = fmaxf(hi, 0.f); }
    ov[k] = (unsigned)f2bf(lo) | ((unsigned)f2bf(hi) << 16);
  }
  uint4 o; o.x = ov[0]; o.y = ov[1]; o.z = ov[2]; o.w = ov[3];
  return o;
}

__global__ void k_gat_agg(const unsigned short* __restrict__ fneigh,
                          const float* __restrict__ attS, const float* __restrict__ attN,
                          const int* __restrict__ rowptr, const int2* __restrict__ edge,
                          unsigned short* __restrict__ out, int N)
{
  const int n = blockIdx.x * 8 + (threadIdx.x >> 5);
  if (n >= N) return;
  const int lane = threadIdx.x & 31;
  const int head = lane >> 2;
  const float as = attS[(size_t)n * NHEAD + head];
  float a[8] = {};
  int p = rowptr[n];
  const int e = rowptr[n + 1];
  for (; p + 1 < e; p += 2) {
    const int2 e0 = edge[p], e1 = edge[p + 1];
    const float c0 = (as + attN[(size_t)e0.x * NHEAD + head]) * __int_as_float(e0.y);
    const float c1 = (as + attN[(size_t)e1.x * NHEAD + head]) * __int_as_float(e1.y);
    const uint4 f0 = *(const uint4*)(fneigh + (size_t)e0.x * D + lane * 8);
    const uint4 f1 = *(const uint4*)(fneigh + (size_t)e1.x * D + lane * 8);
    acc8(a, f0, c0);
    acc8(a, f1, c1);
  }
  if (p < e) {
    const int2 e0 = edge[p];
    const float c0 = (as + attN[(size_t)e0.x * NHEAD + head]) * __int_as_float(e0.y);
    const uint4 f0 = *(const uint4*)(fneigh + (size_t)e0.x * D + lane * 8);
    acc8(a, f0, c0);
  }
  *(uint4*)(out + (size_t)n * D + lane * 8) = pack8(a, false);
}

__global__ void k_gcn_agg(const unsigned short* __restrict__ Hm,
                          const int* __restrict__ rowptr, const int2* __restrict__ edge,
                          unsigned short* __restrict__ out, int N)
{
  const int n = blockIdx.x * 8 + (threadIdx.x >> 5);
  if (n >= N) return;
  const int lane = threadIdx.x & 31;
  float a[8] = {};
  int p = rowptr[n];
  const int e = rowptr[n + 1];
  for (; p + 1 < e; p += 2) {
    const int2 e0 = edge[p], e1 = edge[p + 1];
    const uint4 f0 = *(const uint4*)(Hm + (size_t)e0.x * D + lane * 8);
    const uint4 f1 = *(const uint4*)(Hm + (size_t)e1.x * D + lane * 8);
    acc8(a, f0, __int_as_float(e0.y));
    acc8(a, f1, __int_as_float(e1.y));
  }
  if (p < e) {
    const int2 e0 = edge[p];
    const uint4 f0 = *(const uint4*)(Hm + (size_t)e0.x * D + lane * 8);
    acc8(a, f0, __int_as_float(e0.y));
  }
  *(uint4*)(out + (size_t)n * D + lane * 8) = pack8(a, true);   // relu before BN
}

// ---------------- BatchNorm -------------------------------------------------
__launch_bounds__(256)
__global__ void k_bn_stats(const unsigned short* __restrict__ X, float* __restrict__ sums, int M)
{
  __shared__ float ls[256][8];
  __shared__ float lq[256][8];
  const int t = threadIdx.x, cg = t & 31, rg = t >> 5;
  float s[8] = {}, q[8] = {};
  for (int r = blockIdx.x * 8 + rg; r < M; r += gridDim.x * 8) {
    const uint4 f = *(const uint4*)(X + (size_t)r * D + cg * 8);
    const unsigned w[4] = {f.x, f.y, f.z, f.w};
#pragma unroll
    for (int k = 0; k < 4; ++k) {
      const float lo = bf2f((unsigned short)(w[k] & 0xffff));
      const float hi = bf2f((unsigned short)(w[k] >> 16));
      s[2 * k]     += lo; q[2 * k]     = fmaf(lo, lo, q[2 * k]);
      s[2 * k + 1] += hi; q[2 * k + 1] = fmaf(hi, hi, q[2 * k + 1]);
    }
  }
#pragma unroll
  for (int k = 0; k < 8; ++k) { ls[t][k] = s[k]; lq[t][k] = q[k]; }
  __syncthreads();
  if (rg == 0) {
#pragma unroll
    for (int g = 1; g < 8; ++g)
#pragma unroll
      for (int k = 0; k < 8; ++k) { s[k] += ls[cg + 32 * g][k]; q[k] += lq[cg + 32 * g][k]; }
#pragma unroll
    for (int k = 0; k < 8; ++k) {
      atomicAdd(&sums[cg * 8 + k], s[k]);
      atomicAdd(&sums[D + cg * 8 + k], q[k]);
    }
  }
}

__global__ void k_bn_norm(unsigned short* __restrict__ X, const float* __restrict__ sums, int M)
{
  __shared__ float mu[D], rs[D];
  const int t = threadIdx.x;
  {
    const float m_ = sums[t] / (float)M;
    const float v_ = sums[D + t] / (float)M - m_ * m_;
    mu[t] = m_;
    rs[t] = rsqrtf(v_ + BN_EPS);
  }
  __syncthreads();
  const size_t idx = (size_t)blockIdx.x * 256 + t;   // unit = 8 elems
  const int j0 = (int)((idx * 8) & (D - 1));
  uint4 raw = *(uint4*)(X + idx * 8);
  unsigned int w[4] = {raw.x, raw.y, raw.z, raw.w};
  unsigned int ov[4];
#pragma unroll
  for (int k = 0; k < 4; ++k) {
    const float lo = (bf2f((unsigned short)(w[k] & 0xffff)) - mu[j0 + 2 * k])     * rs[j0 + 2 * k];
    const float hi = (bf2f((unsigned short)(w[k] >> 16))    - mu[j0 + 2 * k + 1]) * rs[j0 + 2 * k + 1];
    ov[k] = (unsigned)f2bf(lo) | ((unsigned)f2bf(hi) << 16);
  }
  uint4 o; o.x = ov[0]; o.y = ov[1]; o.z = ov[2]; o.w = ov[3];
  *(uint4*)(X + idx * 8) = o;
}

// ---------------- Classifier (fused BN norm) --------------------------------
__global__ void k_classifier(const unsigned short* __restrict__ F, const float* __restrict__ W,
                             const float* __restrict__ sums, const float* __restrict__ cls_b,
                             float* __restrict__ out, int N, int baseRow, int writeMode)
{
  const int n = blockIdx.x * 8 + (threadIdx.x >> 5);
  if (n >= N) return;
  const int lane = threadIdx.x & 31;
  const int j0 = lane * 8;
  float mu[8], rs[8];
#pragma unroll
  for (int k = 0; k < 8; ++k) {
    const float m_ = sums[j0 + k] / (float)N;
    const float v_ = sums[D + j0 + k] / (float)N - m_ * m_;
    mu[k] = m_;
    rs[k] = rsqrtf(v_ + BN_EPS);
  }
  const uint4 f = *(const uint4*)(F + (size_t)n * D + j0);
  const unsigned w[4] = {f.x, f.y, f.z, f.w};
  float fv[8];
#pragma unroll
  for (int k = 0; k < 4; ++k) {
    fv[2 * k]     = (bf2f((unsigned short)(w[k] & 0xffff)) - mu[2 * k])     * rs[2 * k];
    fv[2 * k + 1] = (bf2f((unsigned short)(w[k] >> 16))    - mu[2 * k + 1]) * rs[2 * k + 1];
  }
  const float* Wr = W + (size_t)(baseRow + j0) * NCLS;
  float p[NCLS];
#pragma unroll
  for (int c = 0; c < NCLS; ++c) {
    float s = 0.f;
#pragma unroll
    for (int k = 0; k < 8; ++k) s = fmaf(fv[k], Wr[k * NCLS + c], s);
    p[c] = s;
  }
#pragma unroll
  for (int m = 1; m < 32; m <<= 1)
#pragma unroll
    for (int c = 0; c < NCLS; ++c) p[c] += __shfl_xor(p[c], m);
  if (lane == 0) {
    float* o = out + (size_t)n * NCLS;
    if (writeMode) {
#pragma unroll
      for (int c = 0; c < NCLS; ++c) o[c] = cls_b[c] + p[c];
    } else {
#pragma unroll
      for (int c = 0; c < NCLS; ++c) o[c] += p[c];
    }
  }
}

// ---------------------------------------------------------------------------
extern "C" void kernel_launch(void* const* d_in, const int* in_sizes, int n_in,
                              void* d_out, int out_size, void* d_ws, size_t ws_size,
                              hipStream_t stream)
{
  const float* f_in   = (const float*)d_in[0];
  const int*   erow   = (const int*)d_in[1];
  const int*   ecol   = (const int*)d_in[2];
  const float* eval   = (const float*)d_in[3];
  const float* gat_Ws = (const float*)d_in[4];
  const float* gat_bs = (const float*)d_in[5];
  const float* gat_Wn = (const float*)d_in[6];
  const float* gat_bn = (const float*)d_in[7];
  const float* gat_as = (const float*)d_in[8];
  const float* gat_an = (const float*)d_in[9];
  const float* gcn_W  = (const float*)d_in[10];
  const float* gcn_b  = (const float*)d_in[11];
  const float* self_W = (const float*)d_in[12];
  const float* self_b = (const float*)d_in[13];
  const float* cls_W  = (const float*)d_in[14];
  const float* cls_b  = (const float*)d_in[15];
  float* out = (float*)d_out;

  const int N  = in_sizes[0] / D;      // 50000
  const int E  = in_sizes[1] / 4;      // 400000
  const int E4 = 4 * E, N4 = 4 * N;
  const size_t ND = (size_t)N * D;
  const size_t WM = (size_t)D * D;

  // ---- workspace carve-up ----
  unsigned short* F  = (unsigned short*)d_ws;    // f_in bf16; later reused
  unsigned short* O0 = F + ND;                   // O0..O4 contiguous (GEMM slots)
  unsigned short* O1 = O0 + ND;
  unsigned short* O2 = O0 + 2 * ND;
  unsigned short* O3 = O0 + 3 * ND;
  unsigned short* O4 = O0 + 4 * ND;              // self out; Phase-A tmp aliases here
  float* attS   = (float*)(O0 + 5 * ND);
  float* attN   = attS + (size_t)N * NHEAD;
  unsigned short* Wt = (unsigned short*)(attN + (size_t)N * NHEAD);   // 11*65536
  float* bias2  = (float*)(Wt + 11 * WM);        // 11*256
  int*   blkSum = (int*)(bias2 + 11 * D);        // 1024
  int*   rowptr = blkSum + 1024;                 // N4+1 (+pad)
  int2*  edge   = (int2*)(rowptr + N4 + 4);      // E4 (final CSR records)
  float* bnsums = (float*)(edge + E4);           // 9*512  [zeroed]
  // aliases into the edge region (dead before Phase B writes edge):
  int*   cnt     = (int*)edge;                   // N4     [zeroed]
  int*   bfill   = cnt + N4;                     // 1600   [zeroed]
  int*   scanTmp = bfill + 1600;                 // N4
  int2*  tmp     = (int2*)O4;                    // E4 (dead before GEMM1 writes O4)

  const int nb8     = (N + 7) / 8;
  const int scanG   = (N4 + 255) / 256;
  const int buckets = (N4 + 127) >> 7;

  hipMemsetAsync(cnt, 0, ((size_t)N4 + 1600) * sizeof(int), stream);
  hipMemsetAsync(bnsums, 0, 9 * 2 * D * sizeof(float), stream);

  // conversions
  k_cvt  <<<(int)(ND / 8 + 255) / 256, 256, 0, stream>>>(f_in, F, (int)(ND / 8));
  k_cvt_w<<<11 * 256, 256, 0, stream>>>(gat_Ws, gat_Wn, gcn_W, self_W, Wt);
  k_cvt_b<<<11, 256, 0, stream>>>(gat_bs, gat_bn, gcn_b, self_b, bias2);

  // batched CSR (4 adjacencies) with bucketed two-phase scatter
  k_count   <<<(E4 + 255) / 256, 256, 0, stream>>>(erow, cnt, E4, E, N);
  k_scan_blk<<<scanG, 256, 0, stream>>>(cnt, scanTmp, blkSum, N4);
  k_scan_top<<<1, 1024, 0, stream>>>(blkSum, scanG);
  k_scan_fin<<<scanG, 256, 0, stream>>>(scanTmp, blkSum, rowptr, N4);
  k_phaseA  <<<(E4 + 255) / 256, 256, 0, stream>>>(erow, ecol, eval, rowptr, bfill,
                                                   tmp, E4, E, N);
  k_phaseB  <<<buckets, 256, 0, stream>>>(tmp, rowptr, edge, N4);

  const int* rp0 = rowptr;
  const int* rp1 = rowptr + N;
  const int* rp2 = rowptr + 2 * N;
  const int* rp3 = rowptr + 3 * N;
  float* sums = bnsums;   // slot i at sums + i*512
  const int normG = (int)(ND / 8 / 256);

  Tri triF  = {F, F, F};
  Tri triX  = {F, O0, O4};

  // ---- mega GEMM 1: A=F(f_in), cols [att | Wn0 | g0 | g1 | g2 | self] ------
  k_gemm<<<dim3((N + 127) / 128, 6 * 2, 1), 256, 0, stream>>>(
      triF, Wt, bias2, O0, N, 1, 0x22u, gat_as, gat_an, attS, attN);

  // ---- self branch (frees O4 early) ---------------------------------------
  k_bn_stats  <<<256, 256, 0, stream>>>(O4, sums + 8 * 512, N);
  k_classifier<<<nb8, 256, 0, stream>>>(O4, cls_W, sums + 8 * 512, cls_b, out, N, 4 * D, 1);

  // ---- GAT branch ----------------------------------------------------------
  k_gat_agg <<<nb8, 256, 0, stream>>>(O0, attS, attN, rp0, edge, F, N);
  k_bn_stats<<<256, 256, 0, stream>>>(F, sums + 0 * 512, N);
  k_bn_norm <<<normG, 256, 0, stream>>>(F, sums + 0 * 512, N);
  k_gemm<<<dim3((N + 127) / 128, 4, 1), 256, 0, stream>>>(
      triF, Wt + 6 * WM, bias2 + 6 * D, O0, N, 1, 0x02u,
      gat_as + D, gat_an + D, attS, attN);
  k_gat_agg <<<nb8, 256, 0, stream>>>(O0, attS, attN, rp0, edge, F, N);
  k_bn_stats<<<256, 256, 0, stream>>>(F, sums + 1 * 512, N);
  k_classifier<<<nb8, 256, 0, stream>>>(F, cls_W, sums + 1 * 512, cls_b, out, N, 0, 0);

  // ---- 3 GCN branches ------------------------------------------------------
  k_gcn_agg <<<nb8, 256, 0, stream>>>(O1, rp1, edge, F,  N);
  k_gcn_agg <<<nb8, 256, 0, stream>>>(O2, rp2, edge, O0, N);
  k_gcn_agg <<<nb8, 256, 0, stream>>>(O3, rp3, edge, O4, N);
  k_bn_stats<<<256, 256, 0, stream>>>(F,  sums + 2 * 512, N);
  k_bn_stats<<<256, 256, 0, stream>>>(O0, sums + 4 * 512, N);
  k_bn_stats<<<256, 256, 0, stream>>>(O4, sums + 6 * 512, N);
  k_bn_norm <<<normG, 256, 0, stream>>>(F,  sums + 2 * 512, N);
  k_bn_norm <<<normG, 256, 0, stream>>>(O0, sums + 4 * 512, N);
  k_bn_norm <<<normG, 256, 0, stream>>>(O4, sums + 6 * 512, N);
  k_gemm<<<dim3((N + 127) / 128, 2, 3), 256, 0, stream>>>(
      triX, Wt + 8 * WM, bias2 + 8 * D, O1, N, 0, 0x0u,
      nullptr, nullptr, nullptr, nullptr);
  k_gcn_agg <<<nb8, 256, 0, stream>>>(O1, rp1, edge, F,  N);
  k_gcn_agg <<<nb8, 256, 0, stream>>>(O2, rp2, edge, O0, N);
  k_gcn_agg <<<nb8, 256, 0, stream>>>(O3, rp3, edge, O4, N);
  k_bn_stats<<<256, 256, 0, stream>>>(F,  sums + 3 * 512, N);
  k_bn_stats<<<256, 256, 0, stream>>>(O0, sums + 5 * 512, N);
  k_bn_stats<<<256, 256, 0, stream>>>(O4, sums + 7 * 512, N);
  k_classifier<<<nb8, 256, 0, stream>>>(F,  cls_W, sums + 3 * 512, cls_b, out, N, 1 * D, 0);
  k_classifier<<<nb8, 256, 0, stream>>>(O0, cls_W, sums + 5 * 512, cls_b, out, N, 2 * D, 0);
  k_classifier<<<nb8, 256, 0, stream>>>(O4, cls_W, sums + 7 * 512, cls_b, out, N, 3 * D, 0);
}

// Round 6
// 1901.636 us; speedup vs baseline: 2.5772x; 1.0117x over previous
//
#include <hip/hip_runtime.h>

// ---------------------------------------------------------------------------
// ERC GNN forward — round 6:
//  * phaseA buckets 128->8 nodes (r5's 1600-cursor atomic ping-pong was 395us;
//    25000 cursors x ~64 edges restores low contention, keeps 512B windows)
//  * BN-norm passes eliminated: folded into next GEMM weights (W'=rs*W,
//    b'=b-mu*rs@W) via tiny fold kernels
//  * BN stats fused into agg kernels via LDS accumulators (no loop-carried
//    VGPRs -> no r4-style spill); standalone stats only for self branch
// ---------------------------------------------------------------------------

constexpr int D     = 256;
constexpr int NHEAD = 8;
constexpr int NCLS  = 7;
constexpr float BN_EPS = 1e-9f;

typedef short  s16x8 __attribute__((ext_vector_type(8)));
typedef float  f32x4 __attribute__((ext_vector_type(4)));

__device__ __forceinline__ unsigned short f2bf(float f) {
  unsigned int u = __builtin_bit_cast(unsigned int, f);
  u += 0x7FFFu + ((u >> 16) & 1u);          // round-to-nearest-even
  return (unsigned short)(u >> 16);
}
__device__ __forceinline__ float bf2f(unsigned short h) {
  unsigned int u = ((unsigned int)h) << 16;
  return __builtin_bit_cast(float, u);
}

__device__ __forceinline__ void gload_lds16(const void* g, void* l) {
  __builtin_amdgcn_global_load_lds(
      (const __attribute__((address_space(1))) unsigned int*)g,
      (__attribute__((address_space(3))) unsigned int*)l, 16, 0, 0);
}

struct Tri { const unsigned short* a0; const unsigned short* a1; const unsigned short* a2; };

// ---------------- unified bf16 MFMA GEMM ------------------------------------
__launch_bounds__(256)
__global__ void k_gemm(Tri tri, const unsigned short* __restrict__ Wt,
                       const float* __restrict__ bias,
                       unsigned short* __restrict__ Cbase,
                       int M, int attMode, unsigned reluMask,
                       const float* __restrict__ a_s, const float* __restrict__ a_n,
                       float* __restrict__ attS, float* __restrict__ attN)
{
  __shared__ unsigned short As[128 * 32];
  __shared__ unsigned short Bs[128 * 32];
  const int z = blockIdx.z;
  const unsigned short* A = (z == 0) ? tri.a0 : ((z == 1) ? tri.a1 : tri.a2);
  Wt    += (size_t)z * D * D;
  bias  += (size_t)z * D;
  const size_t MD = (size_t)M * D;
  unsigned short* Cz = Cbase + (size_t)z * MD;

  const int t = threadIdx.x;
  const int wave = t >> 6, lane = t & 63;
  const int quad = lane >> 4, l16 = lane & 15;
  const int wm = (wave & 1) * 64, wn = (wave >> 1) * 64;
  const int bm = blockIdx.x * 128, bn = blockIdx.y * 128;
  const int seg = bn >> 8;                    // block lies fully in one segment
  const int att = attMode && (seg == 0);
  const int relu = (reluMask >> seg) & 1;

  f32x4 acc[4][4] = {};

  const int rA0 = wave * 32 + (lane >> 2);
  const int rA1 = rA0 + 16;
  const int sub = (lane & 3) * 8;
  const unsigned short* gA0 = A  + (size_t)min(bm + rA0, M - 1) * D + sub;
  const unsigned short* gA1 = A  + (size_t)min(bm + rA1, M - 1) * D + sub;
  const unsigned short* gB0 = Wt + (size_t)(bn + rA0) * D + sub;
  const unsigned short* gB1 = Wt + (size_t)(bn + rA1) * D + sub;
  unsigned short* lA0 = &As[wave * 1024];
  unsigned short* lA1 = &As[wave * 1024 + 512];
  unsigned short* lB0 = &Bs[wave * 1024];
  unsigned short* lB1 = &Bs[wave * 1024 + 512];

  for (int k0 = 0; k0 < D; k0 += 32) {
    gload_lds16(gA0 + k0, lA0);
    gload_lds16(gA1 + k0, lA1);
    gload_lds16(gB0 + k0, lB0);
    gload_lds16(gB1 + k0, lB1);
    __syncthreads();
    s16x8 af[4], bf[4];
#pragma unroll
    for (int mi = 0; mi < 4; ++mi)
      af[mi] = *(const s16x8*)(&As[(wm + mi * 16 + l16) * 32 + quad * 8]);
#pragma unroll
    for (int nj = 0; nj < 4; ++nj)
      bf[nj] = *(const s16x8*)(&Bs[(wn + nj * 16 + l16) * 32 + quad * 8]);
#pragma unroll
    for (int mi = 0; mi < 4; ++mi)
#pragma unroll
      for (int nj = 0; nj < 4; ++nj)
        acc[mi][nj] = __builtin_amdgcn_mfma_f32_16x16x32_bf16(af[mi], bf[nj], acc[mi][nj], 0, 0, 0);
    __syncthreads();
  }

  // C/D layout: col = l16, row = quad*4 + reg
  if (att) {
    const int hb = (bn + wn) >> 5;
#pragma unroll
    for (int mi = 0; mi < 4; ++mi) {
#pragma unroll
      for (int h = 0; h < 2; ++h) {
        float ps[4] = {}, pn[4] = {};
#pragma unroll
        for (int j = 0; j < 2; ++j) {
          const int nj = h * 2 + j;
          const int col = bn + wn + nj * 16 + l16;
          const float bv = bias[col];
          const float av = a_s[col], nv = a_n[col];
#pragma unroll
          for (int r = 0; r < 4; ++r) {
            const float v = fmaxf(acc[mi][nj][r] + bv, 0.f);
            ps[r] = fmaf(v, av, ps[r]);
            pn[r] = fmaf(v, nv, pn[r]);
          }
        }
#pragma unroll
        for (int m = 1; m < 16; m <<= 1)
#pragma unroll
          for (int r = 0; r < 4; ++r) {
            ps[r] += __shfl_xor(ps[r], m);
            pn[r] += __shfl_xor(pn[r], m);
          }
        if (l16 == 0) {
#pragma unroll
          for (int r = 0; r < 4; ++r) {
            const int row = bm + wm + mi * 16 + quad * 4 + r;
            if (row < M) {
              const float s_ = ps[r], n_ = pn[r];
              attS[(size_t)row * NHEAD + hb + h] = (s_ > 0.f) ? s_ : 0.2f * s_;
              attN[(size_t)row * NHEAD + hb + h] = (n_ > 0.f) ? n_ : 0.2f * n_;
            }
          }
        }
      }
    }
  } else {
    unsigned short* C = Cz + (size_t)(seg - attMode) * MD;
#pragma unroll
    for (int nj = 0; nj < 4; ++nj) {
      const int col = bn + wn + nj * 16 + l16;
      const float bv = bias[col];
      const int cc = col & 255;
#pragma unroll
      for (int mi = 0; mi < 4; ++mi) {
#pragma unroll
        for (int r = 0; r < 4; ++r) {
          const int row = bm + wm + mi * 16 + quad * 4 + r;
          if (row < M) {
            float v = acc[mi][nj][r] + bv;
            if (relu) v = fmaxf(v, 0.f);
            C[(size_t)row * D + cc] = f2bf(v);
          }
        }
      }
    }
  }
}

// ---------------- conversions -----------------------------------------------
__global__ void k_cvt(const float* __restrict__ src, unsigned short* __restrict__ dst, int n8)
{
  const int i = blockIdx.x * 256 + threadIdx.x;
  if (i >= n8) return;
  const float4 a = *(const float4*)(src + (size_t)i * 8);
  const float4 b = *(const float4*)(src + (size_t)i * 8 + 4);
  uint4 o;
  o.x = (unsigned)f2bf(a.x) | ((unsigned)f2bf(a.y) << 16);
  o.y = (unsigned)f2bf(a.z) | ((unsigned)f2bf(a.w) << 16);
  o.z = (unsigned)f2bf(b.x) | ((unsigned)f2bf(b.y) << 16);
  o.w = (unsigned)f2bf(b.z) | ((unsigned)f2bf(b.w) << 16);
  *(uint4*)(dst + (size_t)i * 8) = o;
}

// mega-ordered weights: m 0:Ws0 1:Wn0 2:g0l0 3:g1l0 4:g2l0 5:self 6:Ws1 7:Wn1
//                        8:g0l1 9:g1l1 10:g2l1   -> Wt[m][col j][k d]
__global__ void k_cvt_w(const float* __restrict__ gat_Ws, const float* __restrict__ gat_Wn,
                        const float* __restrict__ gcn_W, const float* __restrict__ self_W,
                        unsigned short* __restrict__ Wt)
{
  const int m = blockIdx.x >> 8, j = blockIdx.x & 255, d = threadIdx.x;
  float v;
  if (m == 0 || m == 1 || m == 6 || m == 7) {
    const int l = (m >= 6) ? 1 : 0;
    const float* W = (m & 1) ? gat_Wn : gat_Ws;          // [L,H,D,DH]
    v = W[(((size_t)l * NHEAD + (j >> 5)) * D + d) * 32 + (j & 31)];
  } else if (m == 5) {
    v = self_W[(size_t)d * D + j];
  } else {
    const int g = (m < 5) ? (m - 2) : (m - 8);
    const int l = (m < 5) ? 0 : 1;
    v = gcn_W[(((size_t)g * 2 + l) * D + d) * D + j];    // [3,L,D,D]
  }
  Wt[((size_t)m * D + j) * D + d] = f2bf(v);
}

__global__ void k_cvt_b(const float* __restrict__ gat_bs, const float* __restrict__ gat_bn,
                        const float* __restrict__ gcn_b, const float* __restrict__ self_b,
                        float* __restrict__ bias2)
{
  const int m = blockIdx.x, j = threadIdx.x;
  float v;
  if (m == 0)       v = gat_bs[j];
  else if (m == 1)  v = gat_bn[j];
  else if (m == 5)  v = self_b[j];
  else if (m == 6)  v = gat_bs[D + j];
  else if (m == 7)  v = gat_bn[D + j];
  else {
    const int g = (m < 5) ? (m - 2) : (m - 8);
    const int l = (m < 5) ? 0 : 1;
    v = gcn_b[((size_t)g * 2 + l) * D + j];
  }
  bias2[(size_t)m * D + j] = v;
}

// ---------------- BN fold: W'[j][k]=rs[k]*W, b'[j]=b[j]-sum_k mu[k]*W'[j][k] -
// launch1: fBase=0, grid.y=2 (Ws1,Wn1, slot 0); launch2: fBase=2, grid.y=3
// (gXl1, slots 2/4/6). WtSrc = Wt+6*WM, biasSrc = bias2+6*D.
__global__ void k_fold(const unsigned short* __restrict__ WtSrc,
                       const float* __restrict__ biasSrc,
                       const float* __restrict__ bnsums,
                       unsigned short* __restrict__ Wt2, float* __restrict__ bias3,
                       int fBase, int M)
{
  __shared__ float red[256];
  const int f = fBase + blockIdx.y;
  const int j = blockIdx.x, k = threadIdx.x;
  const int slot = (f < 2) ? 0 : (2 * f - 2);
  const float* s = bnsums + (size_t)slot * 2 * D;
  const float mu  = s[k] / (float)M;
  const float var = s[D + k] / (float)M - mu * mu;
  const float rs  = rsqrtf(var + BN_EPS);
  const float w2  = bf2f(WtSrc[((size_t)f * D + j) * D + k]) * rs;
  const unsigned short wb = f2bf(w2);
  Wt2[((size_t)f * D + j) * D + k] = wb;
  red[k] = mu * bf2f(wb);
  __syncthreads();
  for (int o = 128; o >= 1; o >>= 1) {
    if (k < o) red[k] += red[k + o];
    __syncthreads();
  }
  if (k == 0) bias3[f * D + j] = biasSrc[f * D + j] - red[0];
}

// ---------------- batched CSR build (4 adjacencies) --------------------------
__global__ void k_count(const int* __restrict__ rows, int* __restrict__ cnt, int E4, int E, int N)
{
  const int i = blockIdx.x * 256 + threadIdx.x;
  if (i < E4) atomicAdd(&cnt[(i / E) * N + rows[i]], 1);
}

__global__ void k_scan_blk(const int* __restrict__ in, int* __restrict__ scanTmp,
                           int* __restrict__ blkSum, int n)
{
  __shared__ int buf[256];
  const int t = threadIdx.x, i = blockIdx.x * 256 + t;
  const int v = (i < n) ? in[i] : 0;
  buf[t] = v; __syncthreads();
  for (int off = 1; off < 256; off <<= 1) {
    const int x = (t >= off) ? buf[t - off] : 0;
    __syncthreads();
    buf[t] += x; __syncthreads();
  }
  if (i < n) scanTmp[i] = buf[t];
  if (t == 255) blkSum[blockIdx.x] = buf[255];
}

__global__ void k_scan_top(int* __restrict__ blkSum, int G)
{
  __shared__ int buf[1024];
  const int t = threadIdx.x;
  const int v = (t < G) ? blkSum[t] : 0;
  buf[t] = v; __syncthreads();
  for (int off = 1; off < 1024; off <<= 1) {
    const int x = (t >= off) ? buf[t - off] : 0;
    __syncthreads();
    buf[t] += x; __syncthreads();
  }
  if (t < G) blkSum[t] = buf[t] - v;
}

__global__ void k_scan_fin(const int* __restrict__ scanTmp, const int* __restrict__ blkOff,
                           int* __restrict__ rowptr, int n)
{
  const int i = blockIdx.x * 256 + threadIdx.x;
  if (i < n) rowptr[i + 1] = scanTmp[i] + blkOff[blockIdx.x];
  if (i == 0) rowptr[0] = 0;
}

// Phase A: scatter into 8-node buckets (25000 cursors: low contention AND
// 512B write windows). tmp record: { (local_row<<17)|col , val_bits }
__global__ void k_phaseA(const int* __restrict__ rows, const int* __restrict__ cols,
                         const float* __restrict__ vals,
                         const int* __restrict__ rowptr, int* __restrict__ bfill,
                         int2* __restrict__ tmp, int E4, int E, int N)
{
  const int i = blockIdx.x * 256 + threadIdx.x;
  if (i >= E4) return;
  const int g = (i / E) * N + rows[i];
  const int b = g >> 3;
  const int p = rowptr[b << 3] + atomicAdd(&bfill[b], 1);
  tmp[p] = make_int2(((g & 7) << 17) | cols[i], __float_as_int(vals[i]));
}

// Phase B: one 64-thread block per bucket; LDS cursors -> final CSR order.
__global__ void k_phaseB(const int2* __restrict__ tmp, const int* __restrict__ rowptr,
                         int2* __restrict__ edge, int N4)
{
  __shared__ int lf[8];
  const int b = blockIdx.x, t = threadIdx.x;
  const int gs = b << 3;
  if (t < 8) lf[t] = rowptr[gs + t];
  __syncthreads();
  const int s = rowptr[gs], e = rowptr[gs + 8];
  for (int i = s + t; i < e; i += 64) {
    const int2 rec = tmp[i];
    const int lr = (rec.x >> 17) & 7;
    const int p = atomicAdd(&lf[lr], 1);
    edge[p] = make_int2(rec.x & 0x1FFFF, rec.y);
  }
}

// ---------------- Aggregations (LDS-accumulated BN stats) -------------------
__device__ __forceinline__ void acc8(float* a, uint4 f, float c) {
  const unsigned w[4] = {f.x, f.y, f.z, f.w};
#pragma unroll
  for (int k = 0; k < 4; ++k) {
    a[2 * k]     = fmaf(c, bf2f((unsigned short)(w[k] & 0xffff)), a[2 * k]);
    a[2 * k + 1] = fmaf(c, bf2f((unsigned short)(w[k] >> 16)),    a[2 * k + 1]);
  }
}

__device__ __forceinline__ uint4 pack8(const float* a) {
  unsigned ov[4];
#pragma unroll
  for (int k = 0; k < 4; ++k)
    ov[k] = (unsigned)f2bf(a[2 * k]) | ((unsigned)f2bf(a[2 * k + 1]) << 16);
  uint4 o; o.x = ov[0]; o.y = ov[1]; o.z = ov[2]; o.w = ov[3];
  return o;
}

__launch_bounds__(256)
__global__ void k_gat_agg(const unsigned short* __restrict__ fneigh,
                          const float* __restrict__ attS, const float* __restrict__ attN,
                          const int* __restrict__ rowptr, const int2* __restrict__ edge,
                          unsigned short* __restrict__ out, float* __restrict__ sums, int N)
{
  __shared__ float shS[D], shQ[D];
  const int t = threadIdx.x;
  shS[t] = 0.f; shQ[t] = 0.f;
  __syncthreads();
  const int grp = t >> 5, lane = t & 31;
  const int head = lane >> 2, c0 = lane * 8;
  for (int n = blockIdx.x * 8 + grp; n < N; n += gridDim.x * 8) {
    const float as = attS[(size_t)n * NHEAD + head];
    float a[8] = {};
    int p = rowptr[n];
    const int e = rowptr[n + 1];
    for (; p + 1 < e; p += 2) {
      const int2 e0 = edge[p], e1 = edge[p + 1];
      const float c0f = (as + attN[(size_t)e0.x * NHEAD + head]) * __int_as_float(e0.y);
      const float c1f = (as + attN[(size_t)e1.x * NHEAD + head]) * __int_as_float(e1.y);
      const uint4 f0 = *(const uint4*)(fneigh + (size_t)e0.x * D + c0);
      const uint4 f1 = *(const uint4*)(fneigh + (size_t)e1.x * D + c0);
      acc8(a, f0, c0f);
      acc8(a, f1, c1f);
    }
    if (p < e) {
      const int2 e0 = edge[p];
      const float c0f = (as + attN[(size_t)e0.x * NHEAD + head]) * __int_as_float(e0.y);
      const uint4 f0 = *(const uint4*)(fneigh + (size_t)e0.x * D + c0);
      acc8(a, f0, c0f);
    }
    *(uint4*)(out + (size_t)n * D + c0) = pack8(a);   // no relu (GAT: BN directly)
#pragma unroll
    for (int k = 0; k < 8; ++k) {
      atomicAdd(&shS[c0 + k], a[k]);
      atomicAdd(&shQ[c0 + k], a[k] * a[k]);
    }
  }
  __syncthreads();
  atomicAdd(&sums[t], shS[t]);
  atomicAdd(&sums[D + t], shQ[t]);
}

__launch_bounds__(256)
__global__ void k_gcn_agg(const unsigned short* __restrict__ Hm,
                          const int* __restrict__ rowptr, const int2* __restrict__ edge,
                          unsigned short* __restrict__ out, float* __restrict__ sums, int N)
{
  __shared__ float shS[D], shQ[D];
  const int t = threadIdx.x;
  shS[t] = 0.f; shQ[t] = 0.f;
  __syncthreads();
  const int grp = t >> 5, lane = t & 31;
  const int c0 = lane * 8;
  for (int n = blockIdx.x * 8 + grp; n < N; n += gridDim.x * 8) {
    float a[8] = {};
    int p = rowptr[n];
    const int e = rowptr[n + 1];
    for (; p + 1 < e; p += 2) {
      const int2 e0 = edge[p], e1 = edge[p + 1];
      const uint4 f0 = *(const uint4*)(Hm + (size_t)e0.x * D + c0);
      const uint4 f1 = *(const uint4*)(Hm + (size_t)e1.x * D + c0);
      acc8(a, f0, __int_as_float(e0.y));
      acc8(a, f1, __int_as_float(e1.y));
    }
    if (p < e) {
      const int2 e0 = edge[p];
      const uint4 f0 = *(const uint4*)(Hm + (size_t)e0.x * D + c0);
      acc8(a, f0, __int_as_float(e0.y));
    }
#pragma unroll
    for (int k = 0; k < 8; ++k) a[k] = fmaxf(a[k], 0.f);   // relu before BN
    *(uint4*)(out + (size_t)n * D + c0) = pack8(a);
#pragma unroll
    for (int k = 0; k < 8; ++k) {
      atomicAdd(&shS[c0 + k], a[k]);
      atomicAdd(&shQ[c0 + k], a[k] * a[k]);
    }
  }
  __syncthreads();
  atomicAdd(&sums[t], shS[t]);
  atomicAdd(&sums[D + t], shQ[t]);
}

// ---------------- BatchNorm stats (self branch only) ------------------------
__launch_bounds__(256)
__global__ void k_bn_stats(const unsigned short* __restrict__ X, float* __restrict__ sums, int M)
{
  __shared__ float ls[256][8];
  __shared__ float lq[256][8];
  const int t = threadIdx.x, cg = t & 31, rg = t >> 5;
  float s[8] = {}, q[8] = {};
  for (int r = blockIdx.x * 8 + rg; r < M; r += gridDim.x * 8) {
    const uint4 f = *(const uint4*)(X + (size_t)r * D + cg * 8);
    const unsigned w[4] = {f.x, f.y, f.z, f.w};
#pragma unroll
    for (int k = 0; k < 4; ++k) {
      const float lo = bf2f((unsigned short)(w[k] & 0xffff));
      const float hi = bf2f((unsigned short)(w[k] >> 16));
      s[2 * k]     += lo; q[2 * k]     = fmaf(lo, lo, q[2 * k]);
      s[2 * k + 1] += hi; q[2 * k + 1] = fmaf(hi, hi, q[2 * k + 1]);
    }
  }
#pragma unroll
  for (int k = 0; k < 8; ++k) { ls[t][k] = s[k]; lq[t][k] = q[k]; }
  __syncthreads();
  if (rg == 0) {
#pragma unroll
    for (int g = 1; g < 8; ++g)
#pragma unroll
      for (int k = 0; k < 8; ++k) { s[k] += ls[cg + 32 * g][k]; q[k] += lq[cg + 32 * g][k]; }
#pragma unroll
    for (int k = 0; k < 8; ++k) {
      atomicAdd(&sums[cg * 8 + k], s[k]);
      atomicAdd(&sums[D + cg * 8 + k], q[k]);
    }
  }
}

// ---------------- Classifier (fused BN norm) --------------------------------
__global__ void k_classifier(const unsigned short* __restrict__ F, const float* __restrict__ W,
                             const float* __restrict__ sums, const float* __restrict__ cls_b,
                             float* __restrict__ out, int N, int baseRow, int writeMode)
{
  const int n = blockIdx.x * 8 + (threadIdx.x >> 5);
  if (n >= N) return;
  const int lane = threadIdx.x & 31;
  const int j0 = lane * 8;
  float mu[8], rs[8];
#pragma unroll
  for (int k = 0; k < 8; ++k) {
    const float m_ = sums[j0 + k] / (float)N;
    const float v_ = sums[D + j0 + k] / (float)N - m_ * m_;
    mu[k] = m_;
    rs[k] = rsqrtf(v_ + BN_EPS);
  }
  const uint4 f = *(const uint4*)(F + (size_t)n * D + j0);
  const unsigned w[4] = {f.x, f.y, f.z, f.w};
  float fv[8];
#pragma unroll
  for (int k = 0; k < 4; ++k) {
    fv[2 * k]     = (bf2f((unsigned short)(w[k] & 0xffff)) - mu[2 * k])     * rs[2 * k];
    fv[2 * k + 1] = (bf2f((unsigned short)(w[k] >> 16))    - mu[2 * k + 1]) * rs[2 * k + 1];
  }
  const float* Wr = W + (size_t)(baseRow + j0) * NCLS;
  float p[NCLS];
#pragma unroll
  for (int c = 0; c < NCLS; ++c) {
    float s = 0.f;
#pragma unroll
    for (int k = 0; k < 8; ++k) s = fmaf(fv[k], Wr[k * NCLS + c], s);
    p[c] = s;
  }
#pragma unroll
  for (int m = 1; m < 32; m <<= 1)
#pragma unroll
    for (int c = 0; c < NCLS; ++c) p[c] += __shfl_xor(p[c], m);
  if (lane == 0) {
    float* o = out + (size_t)n * NCLS;
    if (writeMode) {
#pragma unroll
      for (int c = 0; c < NCLS; ++c) o[c] = cls_b[c] + p[c];
    } else {
#pragma unroll
      for (int c = 0; c < NCLS; ++c) o[c] += p[c];
    }
  }
}

// ---------------------------------------------------------------------------
extern "C" void kernel_launch(void* const* d_in, const int* in_sizes, int n_in,
                              void* d_out, int out_size, void* d_ws, size_t ws_size,
                              hipStream_t stream)
{
  const float* f_in   = (const float*)d_in[0];
  const int*   erow   = (const int*)d_in[1];
  const int*   ecol   = (const int*)d_in[2];
  const float* eval   = (const float*)d_in[3];
  const float* gat_Ws = (const float*)d_in[4];
  const float* gat_bs = (const float*)d_in[5];
  const float* gat_Wn = (const float*)d_in[6];
  const float* gat_bn = (const float*)d_in[7];
  const float* gat_as = (const float*)d_in[8];
  const float* gat_an = (const float*)d_in[9];
  const float* gcn_W  = (const float*)d_in[10];
  const float* gcn_b  = (const float*)d_in[11];
  const float* self_W = (const float*)d_in[12];
  const float* self_b = (const float*)d_in[13];
  const float* cls_W  = (const float*)d_in[14];
  const float* cls_b  = (const float*)d_in[15];
  float* out = (float*)d_out;

  const int N  = in_sizes[0] / D;      // 50000
  const int E  = in_sizes[1] / 4;      // 400000
  const int E4 = 4 * E, N4 = 4 * N;
  const size_t ND = (size_t)N * D;
  const size_t WM = (size_t)D * D;
  const int buckets = N4 >> 3;         // 25000 (8-node buckets)

  // ---- workspace carve-up ----
  unsigned short* F  = (unsigned short*)d_ws;    // f_in bf16; recycled later
  unsigned short* O0 = F + ND;                   // O0..O4 contiguous (GEMM slots)
  unsigned short* O1 = O0 + ND;
  unsigned short* O2 = O0 + 2 * ND;
  unsigned short* O3 = O0 + 3 * ND;
  unsigned short* O4 = O0 + 4 * ND;              // self out; Phase-A tmp aliases here
  float* attS   = (float*)(O0 + 5 * ND);
  float* attN   = attS + (size_t)N * NHEAD;
  unsigned short* Wt  = (unsigned short*)(attN + (size_t)N * NHEAD);  // 11*65536
  unsigned short* Wt2 = Wt + 11 * WM;            // 5*65536 (folded L1 weights)
  float* bias2  = (float*)(Wt2 + 5 * WM);        // 11*256
  float* bias3  = bias2 + 11 * D;                // 5*256 (folded biases)
  int*   blkSum = (int*)(bias3 + 5 * D);         // 1024
  int*   rowptr = blkSum + 1024;                 // N4+1 (+pad)
  int2*  edge   = (int2*)(rowptr + N4 + 4);      // E4 (final CSR records)
  float* bnsums = (float*)(edge + E4);           // 9*512  [zeroed]
  // aliases into the edge region (dead before Phase B writes edge):
  int*   cnt     = (int*)edge;                   // N4     [zeroed]
  int*   bfill   = cnt + N4;                     // buckets [zeroed]
  int*   scanTmp = bfill + buckets;              // N4
  int2*  tmp     = (int2*)O4;                    // E4 (dead before GEMM1 writes O4)

  const int nb8   = (N + 7) / 8;
  const int scanG = (N4 + 255) / 256;
  const int aggG  = 512;

  hipMemsetAsync(cnt, 0, ((size_t)N4 + buckets) * sizeof(int), stream);
  hipMemsetAsync(bnsums, 0, 9 * 2 * D * sizeof(float), stream);

  // conversions
  k_cvt  <<<(int)(ND / 8 + 255) / 256, 256, 0, stream>>>(f_in, F, (int)(ND / 8));
  k_cvt_w<<<11 * 256, 256, 0, stream>>>(gat_Ws, gat_Wn, gcn_W, self_W, Wt);
  k_cvt_b<<<11, 256, 0, stream>>>(gat_bs, gat_bn, gcn_b, self_b, bias2);

  // batched CSR (4 adjacencies), two-phase with 8-node buckets
  k_count   <<<(E4 + 255) / 256, 256, 0, stream>>>(erow, cnt, E4, E, N);
  k_scan_blk<<<scanG, 256, 0, stream>>>(cnt, scanTmp, blkSum, N4);
  k_scan_top<<<1, 1024, 0, stream>>>(blkSum, scanG);
  k_scan_fin<<<scanG, 256, 0, stream>>>(scanTmp, blkSum, rowptr, N4);
  k_phaseA  <<<(E4 + 255) / 256, 256, 0, stream>>>(erow, ecol, eval, rowptr, bfill,
                                                   tmp, E4, E, N);
  k_phaseB  <<<buckets, 64, 0, stream>>>(tmp, rowptr, edge, N4);

  const int* rp0 = rowptr;
  const int* rp1 = rowptr + N;
  const int* rp2 = rowptr + 2 * N;
  const int* rp3 = rowptr + 3 * N;
  float* sums = bnsums;   // slot i at sums + i*512

  Tri triF = {F, F, F};
  Tri triX = {F, O0, O4};

  // ---- mega GEMM 1: A=F(f_in), segs [att | Wn0 | g0 | g1 | g2 | self] ------
  k_gemm<<<dim3((N + 127) / 128, 12, 1), 256, 0, stream>>>(
      triF, Wt, bias2, O0, N, 1, 0x22u, gat_as, gat_an, attS, attN);

  // ---- self branch (frees O4 early) ---------------------------------------
  k_bn_stats  <<<256, 256, 0, stream>>>(O4, sums + 8 * 512, N);
  k_classifier<<<nb8, 256, 0, stream>>>(O4, cls_W, sums + 8 * 512, cls_b, out, N, 4 * D, 1);

  // ---- GAT branch ----------------------------------------------------------
  k_gat_agg<<<aggG, 256, 0, stream>>>(O0, attS, attN, rp0, edge, F, sums + 0 * 512, N);
  k_fold   <<<dim3(256, 2), 256, 0, stream>>>(Wt + 6 * WM, bias2 + 6 * D, bnsums,
                                              Wt2, bias3, 0, N);
  k_gemm<<<dim3((N + 127) / 128, 4, 1), 256, 0, stream>>>(
      triF, Wt2, bias3, O0, N, 1, 0x02u, gat_as + D, gat_an + D, attS, attN);
  k_gat_agg<<<aggG, 256, 0, stream>>>(O0, attS, attN, rp0, edge, F, sums + 1 * 512, N);
  k_classifier<<<nb8, 256, 0, stream>>>(F, cls_W, sums + 1 * 512, cls_b, out, N, 0, 0);

  // ---- 3 GCN branches ------------------------------------------------------
  k_gcn_agg<<<aggG, 256, 0, stream>>>(O1, rp1, edge, F,  sums + 2 * 512, N);
  k_gcn_agg<<<aggG, 256, 0, stream>>>(O2, rp2, edge, O0, sums + 4 * 512, N);
  k_gcn_agg<<<aggG, 256, 0, stream>>>(O3, rp3, edge, O4, sums + 6 * 512, N);
  k_fold   <<<dim3(256, 3), 256, 0, stream>>>(Wt + 6 * WM, bias2 + 6 * D, bnsums,
                                              Wt2, bias3, 2, N);
  k_gemm<<<dim3((N + 127) / 128, 2, 3), 256, 0, stream>>>(
      triX, Wt2 + 2 * WM, bias3 + 2 * D, O1, N, 0, 0x0u,
      nullptr, nullptr, nullptr, nullptr);
  k_gcn_agg<<<aggG, 256, 0, stream>>>(O1, rp1, edge, F,  sums + 3 * 512, N);
  k_gcn_agg<<<aggG, 256, 0, stream>>>(O2, rp2, edge, O0, sums + 5 * 512, N);
  k_gcn_agg<<<aggG, 256, 0, stream>>>(O3, rp3, edge, O4, sums + 7 * 512, N);
  k_classifier<<<nb8, 256, 0, stream>>>(F,  cls_W, sums + 3 * 512, cls_b, out, N, 1 * D, 0);
  k_classifier<<<nb8, 256, 0, stream>>>(O0, cls_W, sums + 5 * 512, cls_b, out, N, 2 * D, 0);
  k_classifier<<<nb8, 256, 0, stream>>>(O4, cls_W, sums + 7 * 512, cls_b, out, N, 3 * D, 0);
}

// Round 7
// 1500.416 us; speedup vs baseline: 3.2663x; 1.2674x over previous
//
#include <hip/hip_runtime.h>

// ---------------------------------------------------------------------------
// ERC GNN forward — round 7:
//  * GEMM: y-fastest 1D grid (A-tile LLC reuse; r6 FETCH was 6x A) and
//    LDS-staged uint4 epilogue (r6 2B scalar C stores gave 1.9x write amp)
//  * aggs reverted to r5 one-shot form (r6 LDS-atomic stats fusion serialized);
//    standalone bn_stats passes again
//  * keep: 8-node-bucket two-phase scatter, BN weight-fold, classifier-fused
//    BN, mega/batched GEMMs, fused GAT attention epilogue
// ---------------------------------------------------------------------------

constexpr int D     = 256;
constexpr int NHEAD = 8;
constexpr int NCLS  = 7;
constexpr float BN_EPS = 1e-9f;

typedef short  s16x8 __attribute__((ext_vector_type(8)));
typedef float  f32x4 __attribute__((ext_vector_type(4)));

__device__ __forceinline__ unsigned short f2bf(float f) {
  unsigned int u = __builtin_bit_cast(unsigned int, f);
  u += 0x7FFFu + ((u >> 16) & 1u);          // round-to-nearest-even
  return (unsigned short)(u >> 16);
}
__device__ __forceinline__ float bf2f(unsigned short h) {
  unsigned int u = ((unsigned int)h) << 16;
  return __builtin_bit_cast(float, u);
}

__device__ __forceinline__ void gload_lds16(const void* g, void* l) {
  __builtin_amdgcn_global_load_lds(
      (const __attribute__((address_space(1))) unsigned int*)g,
      (__attribute__((address_space(3))) unsigned int*)l, 16, 0, 0);
}

struct Tri { const unsigned short* a0; const unsigned short* a1; const unsigned short* a2; };

// ---------------- unified bf16 MFMA GEMM ------------------------------------
// 1D x-grid: by = bid % ny (col stripe, fastest), bx = bid / ny (row block).
// C_seg[M,256] = A[M,256] @ Wt_seg^T + bias_seg per 256-col segment.
// attMode: segment 0 computes fused GAT attention only (no C store).
__launch_bounds__(256)
__global__ void k_gemm(Tri tri, const unsigned short* __restrict__ Wt,
                       const float* __restrict__ bias,
                       unsigned short* __restrict__ Cbase,
                       int M, int ny, int attMode, unsigned reluMask,
                       const float* __restrict__ a_s, const float* __restrict__ a_n,
                       float* __restrict__ attS, float* __restrict__ attN)
{
  __shared__ unsigned short sh[8448];        // As[4096] | Bs[4096]; Cs[64*132]
  unsigned short* As = sh;
  unsigned short* Bs = sh + 4096;
  const int z = blockIdx.z;
  const unsigned short* A = (z == 0) ? tri.a0 : ((z == 1) ? tri.a1 : tri.a2);
  Wt    += (size_t)z * D * D;
  bias  += (size_t)z * D;
  const size_t MD = (size_t)M * D;
  unsigned short* Cz = Cbase + (size_t)z * MD;

  const int t = threadIdx.x;
  const int wave = t >> 6, lane = t & 63;
  const int quad = lane >> 4, l16 = lane & 15;
  const int wm = (wave & 1) * 64, wn = (wave >> 1) * 64;
  const int bx = blockIdx.x / ny, by = blockIdx.x % ny;
  const int bm = bx * 128, bn = by * 128;
  const int seg = bn >> 8;                    // block lies fully in one segment
  const int att = attMode && (seg == 0);
  const int relu = (reluMask >> seg) & 1;

  f32x4 acc[4][4] = {};

  const int rA0 = wave * 32 + (lane >> 2);
  const int rA1 = rA0 + 16;
  const int sub = (lane & 3) * 8;
  const unsigned short* gA0 = A  + (size_t)min(bm + rA0, M - 1) * D + sub;
  const unsigned short* gA1 = A  + (size_t)min(bm + rA1, M - 1) * D + sub;
  const unsigned short* gB0 = Wt + (size_t)(bn + rA0) * D + sub;
  const unsigned short* gB1 = Wt + (size_t)(bn + rA1) * D + sub;
  unsigned short* lA0 = &As[wave * 1024];
  unsigned short* lA1 = &As[wave * 1024 + 512];
  unsigned short* lB0 = &Bs[wave * 1024];
  unsigned short* lB1 = &Bs[wave * 1024 + 512];

  for (int k0 = 0; k0 < D; k0 += 32) {
    gload_lds16(gA0 + k0, lA0);
    gload_lds16(gA1 + k0, lA1);
    gload_lds16(gB0 + k0, lB0);
    gload_lds16(gB1 + k0, lB1);
    __syncthreads();
    s16x8 af[4], bf[4];
#pragma unroll
    for (int mi = 0; mi < 4; ++mi)
      af[mi] = *(const s16x8*)(&As[(wm + mi * 16 + l16) * 32 + quad * 8]);
#pragma unroll
    for (int nj = 0; nj < 4; ++nj)
      bf[nj] = *(const s16x8*)(&Bs[(wn + nj * 16 + l16) * 32 + quad * 8]);
#pragma unroll
    for (int mi = 0; mi < 4; ++mi)
#pragma unroll
      for (int nj = 0; nj < 4; ++nj)
        acc[mi][nj] = __builtin_amdgcn_mfma_f32_16x16x32_bf16(af[mi], bf[nj], acc[mi][nj], 0, 0, 0);
    __syncthreads();
  }

  // C/D layout: col = l16, row = quad*4 + reg
  if (att) {
    const int hb = (bn + wn) >> 5;
#pragma unroll
    for (int mi = 0; mi < 4; ++mi) {
#pragma unroll
      for (int h = 0; h < 2; ++h) {
        float ps[4] = {}, pn[4] = {};
#pragma unroll
        for (int j = 0; j < 2; ++j) {
          const int nj = h * 2 + j;
          const int col = bn + wn + nj * 16 + l16;
          const float bv = bias[col];
          const float av = a_s[col], nv = a_n[col];
#pragma unroll
          for (int r = 0; r < 4; ++r) {
            const float v = fmaxf(acc[mi][nj][r] + bv, 0.f);
            ps[r] = fmaf(v, av, ps[r]);
            pn[r] = fmaf(v, nv, pn[r]);
          }
        }
#pragma unroll
        for (int m = 1; m < 16; m <<= 1)
#pragma unroll
          for (int r = 0; r < 4; ++r) {
            ps[r] += __shfl_xor(ps[r], m);
            pn[r] += __shfl_xor(pn[r], m);
          }
        if (l16 == 0) {
#pragma unroll
          for (int r = 0; r < 4; ++r) {
            const int row = bm + wm + mi * 16 + quad * 4 + r;
            if (row < M) {
              const float s_ = ps[r], n_ = pn[r];
              attS[(size_t)row * NHEAD + hb + h] = (s_ > 0.f) ? s_ : 0.2f * s_;
              attN[(size_t)row * NHEAD + hb + h] = (n_ > 0.f) ? n_ : 0.2f * n_;
            }
          }
        }
      }
    }
  } else {
    // LDS-staged epilogue: two 64-row passes, padded stride 132 (conflict-free)
    unsigned short* C = Cz + (size_t)(seg - attMode) * MD;
    const int cbase = bn & 255;
#pragma unroll
    for (int p = 0; p < 2; ++p) {
      if ((wave & 1) == p) {
#pragma unroll
        for (int nj = 0; nj < 4; ++nj) {
          const int lcol = wn + nj * 16 + l16;
          const float bv = bias[bn + lcol];
#pragma unroll
          for (int mi = 0; mi < 4; ++mi) {
#pragma unroll
            for (int r = 0; r < 4; ++r) {
              float v = acc[mi][nj][r] + bv;
              if (relu) v = fmaxf(v, 0.f);
              sh[(mi * 16 + quad * 4 + r) * 132 + lcol] = f2bf(v);
            }
          }
        }
      }
      __syncthreads();
#pragma unroll
      for (int k = 0; k < 4; ++k) {
        const int idx = k * 256 + t;          // 1024 uint4 = 64 rows x 16
        const int row = idx >> 4;
        const int cb  = (idx & 15) * 8;
        const int grow = bm + p * 64 + row;
        if (grow < M)
          *(uint4*)(C + (size_t)grow * D + cbase + cb) = *(const uint4*)(&sh[row * 132 + cb]);
      }
      __syncthreads();
    }
  }
}

// ---------------- conversions -----------------------------------------------
__global__ void k_cvt(const float* __restrict__ src, unsigned short* __restrict__ dst, int n8)
{
  const int i = blockIdx.x * 256 + threadIdx.x;
  if (i >= n8) return;
  const float4 a = *(const float4*)(src + (size_t)i * 8);
  const float4 b = *(const float4*)(src + (size_t)i * 8 + 4);
  uint4 o;
  o.x = (unsigned)f2bf(a.x) | ((unsigned)f2bf(a.y) << 16);
  o.y = (unsigned)f2bf(a.z) | ((unsigned)f2bf(a.w) << 16);
  o.z = (unsigned)f2bf(b.x) | ((unsigned)f2bf(b.y) << 16);
  o.w = (unsigned)f2bf(b.z) | ((unsigned)f2bf(b.w) << 16);
  *(uint4*)(dst + (size_t)i * 8) = o;
}

// mega-ordered weights: m 0:Ws0 1:Wn0 2:g0l0 3:g1l0 4:g2l0 5:self 6:Ws1 7:Wn1
//                        8:g0l1 9:g1l1 10:g2l1   -> Wt[m][col j][k d]
__global__ void k_cvt_w(const float* __restrict__ gat_Ws, const float* __restrict__ gat_Wn,
                        const float* __restrict__ gcn_W, const float* __restrict__ self_W,
                        unsigned short* __restrict__ Wt)
{
  const int m = blockIdx.x >> 8, j = blockIdx.x & 255, d = threadIdx.x;
  float v;
  if (m == 0 || m == 1 || m == 6 || m == 7) {
    const int l = (m >= 6) ? 1 : 0;
    const float* W = (m & 1) ? gat_Wn : gat_Ws;          // [L,H,D,DH]
    v = W[(((size_t)l * NHEAD + (j >> 5)) * D + d) * 32 + (j & 31)];
  } else if (m == 5) {
    v = self_W[(size_t)d * D + j];
  } else {
    const int g = (m < 5) ? (m - 2) : (m - 8);
    const int l = (m < 5) ? 0 : 1;
    v = gcn_W[(((size_t)g * 2 + l) * D + d) * D + j];    // [3,L,D,D]
  }
  Wt[((size_t)m * D + j) * D + d] = f2bf(v);
}

__global__ void k_cvt_b(const float* __restrict__ gat_bs, const float* __restrict__ gat_bn,
                        const float* __restrict__ gcn_b, const float* __restrict__ self_b,
                        float* __restrict__ bias2)
{
  const int m = blockIdx.x, j = threadIdx.x;
  float v;
  if (m == 0)       v = gat_bs[j];
  else if (m == 1)  v = gat_bn[j];
  else if (m == 5)  v = self_b[j];
  else if (m == 6)  v = gat_bs[D + j];
  else if (m == 7)  v = gat_bn[D + j];
  else {
    const int g = (m < 5) ? (m - 2) : (m - 8);
    const int l = (m < 5) ? 0 : 1;
    v = gcn_b[((size_t)g * 2 + l) * D + j];
  }
  bias2[(size_t)m * D + j] = v;
}

// ---------------- BN fold: W'[j][k]=rs[k]*W, b'[j]=b[j]-sum_k mu[k]*W'[j][k] -
__global__ void k_fold(const unsigned short* __restrict__ WtSrc,
                       const float* __restrict__ biasSrc,
                       const float* __restrict__ bnsums,
                       unsigned short* __restrict__ Wt2, float* __restrict__ bias3,
                       int fBase, int M)
{
  __shared__ float red[256];
  const int f = fBase + blockIdx.y;
  const int j = blockIdx.x, k = threadIdx.x;
  const int slot = (f < 2) ? 0 : (2 * f - 2);
  const float* s = bnsums + (size_t)slot * 2 * D;
  const float mu  = s[k] / (float)M;
  const float var = s[D + k] / (float)M - mu * mu;
  const float rs  = rsqrtf(var + BN_EPS);
  const float w2  = bf2f(WtSrc[((size_t)f * D + j) * D + k]) * rs;
  const unsigned short wb = f2bf(w2);
  Wt2[((size_t)f * D + j) * D + k] = wb;
  red[k] = mu * bf2f(wb);
  __syncthreads();
  for (int o = 128; o >= 1; o >>= 1) {
    if (k < o) red[k] += red[k + o];
    __syncthreads();
  }
  if (k == 0) bias3[f * D + j] = biasSrc[f * D + j] - red[0];
}

// ---------------- batched CSR build (4 adjacencies) --------------------------
__global__ void k_count(const int* __restrict__ rows, int* __restrict__ cnt, int E4, int E, int N)
{
  const int i = blockIdx.x * 256 + threadIdx.x;
  if (i < E4) atomicAdd(&cnt[(i / E) * N + rows[i]], 1);
}

__global__ void k_scan_blk(const int* __restrict__ in, int* __restrict__ scanTmp,
                           int* __restrict__ blkSum, int n)
{
  __shared__ int buf[256];
  const int t = threadIdx.x, i = blockIdx.x * 256 + t;
  const int v = (i < n) ? in[i] : 0;
  buf[t] = v; __syncthreads();
  for (int off = 1; off < 256; off <<= 1) {
    const int x = (t >= off) ? buf[t - off] : 0;
    __syncthreads();
    buf[t] += x; __syncthreads();
  }
  if (i < n) scanTmp[i] = buf[t];
  if (t == 255) blkSum[blockIdx.x] = buf[255];
}

__global__ void k_scan_top(int* __restrict__ blkSum, int G)
{
  __shared__ int buf[1024];
  const int t = threadIdx.x;
  const int v = (t < G) ? blkSum[t] : 0;
  buf[t] = v; __syncthreads();
  for (int off = 1; off < 1024; off <<= 1) {
    const int x = (t >= off) ? buf[t - off] : 0;
    __syncthreads();
    buf[t] += x; __syncthreads();
  }
  if (t < G) blkSum[t] = buf[t] - v;
}

__global__ void k_scan_fin(const int* __restrict__ scanTmp, const int* __restrict__ blkOff,
                           int* __restrict__ rowptr, int n)
{
  const int i = blockIdx.x * 256 + threadIdx.x;
  if (i < n) rowptr[i + 1] = scanTmp[i] + blkOff[blockIdx.x];
  if (i == 0) rowptr[0] = 0;
}

// Phase A: scatter into 8-node buckets. record { (local_row<<17)|col, val }
__global__ void k_phaseA(const int* __restrict__ rows, const int* __restrict__ cols,
                         const float* __restrict__ vals,
                         const int* __restrict__ rowptr, int* __restrict__ bfill,
                         int2* __restrict__ tmp, int E4, int E, int N)
{
  const int i = blockIdx.x * 256 + threadIdx.x;
  if (i >= E4) return;
  const int g = (i / E) * N + rows[i];
  const int b = g >> 3;
  const int p = rowptr[b << 3] + atomicAdd(&bfill[b], 1);
  tmp[p] = make_int2(((g & 7) << 17) | cols[i], __float_as_int(vals[i]));
}

// Phase B: one 64-thread block per bucket; LDS cursors -> final CSR order.
__global__ void k_phaseB(const int2* __restrict__ tmp, const int* __restrict__ rowptr,
                         int2* __restrict__ edge, int N4)
{
  __shared__ int lf[8];
  const int b = blockIdx.x, t = threadIdx.x;
  const int gs = b << 3;
  if (t < 8) lf[t] = rowptr[gs + t];
  __syncthreads();
  const int s = rowptr[gs], e = rowptr[gs + 8];
  for (int i = s + t; i < e; i += 64) {
    const int2 rec = tmp[i];
    const int lr = (rec.x >> 17) & 7;
    const int p = atomicAdd(&lf[lr], 1);
    edge[p] = make_int2(rec.x & 0x1FFFF, rec.y);
  }
}

// ---------------- Aggregations (one-shot r5 form) ---------------------------
__device__ __forceinline__ void acc8(float* a, uint4 f, float c) {
  const unsigned w[4] = {f.x, f.y, f.z, f.w};
#pragma unroll
  for (int k = 0; k < 4; ++k) {
    a[2 * k]     = fmaf(c, bf2f((unsigned short)(w[k] & 0xffff)), a[2 * k]);
    a[2 * k + 1] = fmaf(c, bf2f((unsigned short)(w[k] >> 16)),    a[2 * k + 1]);
  }
}

__device__ __forceinline__ uint4 pack8(const float* a, bool relu) {
  unsigned ov[4];
#pragma unroll
  for (int k = 0; k < 4; ++k) {
    float lo = a[2 * k], hi = a[2 * k + 1];
    if (relu) { lo = fmaxf(lo, 0.f); hi = fmaxf(hi, 0.f); }
    ov[k] = (unsigned)f2bf(lo) | ((unsigned)f2bf(hi) << 16);
  }
  uint4 o; o.x = ov[0]; o.y = ov[1]; o.z = ov[2]; o.w = ov[3];
  return o;
}

__global__ void k_gat_agg(const unsigned short* __restrict__ fneigh,
                          const float* __restrict__ attS, const float* __restrict__ attN,
                          const int* __restrict__ rowptr, const int2* __restrict__ edge,
                          unsigned short* __restrict__ out, int N)
{
  const int n = blockIdx.x * 8 + (threadIdx.x >> 5);
  if (n >= N) return;
  const int lane = threadIdx.x & 31;
  const int head = lane >> 2;
  const float as = attS[(size_t)n * NHEAD + head];
  float a[8] = {};
  int p = rowptr[n];
  const int e = rowptr[n + 1];
  for (; p + 1 < e; p += 2) {
    const int2 e0 = edge[p], e1 = edge[p + 1];
    const float c0 = (as + attN[(size_t)e0.x * NHEAD + head]) * __int_as_float(e0.y);
    const float c1 = (as + attN[(size_t)e1.x * NHEAD + head]) * __int_as_float(e1.y);
    const uint4 f0 = *(const uint4*)(fneigh + (size_t)e0.x * D + lane * 8);
    const uint4 f1 = *(const uint4*)(fneigh + (size_t)e1.x * D + lane * 8);
    acc8(a, f0, c0);
    acc8(a, f1, c1);
  }
  if (p < e) {
    const int2 e0 = edge[p];
    const float c0 = (as + attN[(size_t)e0.x * NHEAD + head]) * __int_as_float(e0.y);
    const uint4 f0 = *(const uint4*)(fneigh + (size_t)e0.x * D + lane * 8);
    acc8(a, f0, c0);
  }
  *(uint4*)(out + (size_t)n * D + lane * 8) = pack8(a, false);
}

__global__ void k_gcn_agg(const unsigned short* __restrict__ Hm,
                          const int* __restrict__ rowptr, const int2* __restrict__ edge,
                          unsigned short* __restrict__ out, int N)
{
  const int n = blockIdx.x * 8 + (threadIdx.x >> 5);
  if (n >= N) return;
  const int lane = threadIdx.x & 31;
  float a[8] = {};
  int p = rowptr[n];
  const int e = rowptr[n + 1];
  for (; p + 1 < e; p += 2) {
    const int2 e0 = edge[p], e1 = edge[p + 1];
    const uint4 f0 = *(const uint4*)(Hm + (size_t)e0.x * D + lane * 8);
    const uint4 f1 = *(const uint4*)(Hm + (size_t)e1.x * D + lane * 8);
    acc8(a, f0, __int_as_float(e0.y));
    acc8(a, f1, __int_as_float(e1.y));
  }
  if (p < e) {
    const int2 e0 = edge[p];
    const uint4 f0 = *(const uint4*)(Hm + (size_t)e0.x * D + lane * 8);
    acc8(a, f0, __int_as_float(e0.y));
  }
  *(uint4*)(out + (size_t)n * D + lane * 8) = pack8(a, true);   // relu before BN
}

// ---------------- BatchNorm stats -------------------------------------------
__launch_bounds__(256)
__global__ void k_bn_stats(const unsigned short* __restrict__ X, float* __restrict__ sums, int M)
{
  __shared__ float ls[256][8];
  __shared__ float lq[256][8];
  const int t = threadIdx.x, cg = t & 31, rg = t >> 5;
  float s[8] = {}, q[8] = {};
  for (int r = blockIdx.x * 8 + rg; r < M; r += gridDim.x * 8) {
    const uint4 f = *(const uint4*)(X + (size_t)r * D + cg * 8);
    const unsigned w[4] = {f.x, f.y, f.z, f.w};
#pragma unroll
    for (int k = 0; k < 4; ++k) {
      const float lo = bf2f((unsigned short)(w[k] & 0xffff));
      const float hi = bf2f((unsigned short)(w[k] >> 16));
      s[2 * k]     += lo; q[2 * k]     = fmaf(lo, lo, q[2 * k]);
      s[2 * k + 1] += hi; q[2 * k + 1] = fmaf(hi, hi, q[2 * k + 1]);
    }
  }
#pragma unroll
  for (int k = 0; k < 8; ++k) { ls[t][k] = s[k]; lq[t][k] = q[k]; }
  __syncthreads();
  if (rg == 0) {
#pragma unroll
    for (int g = 1; g < 8; ++g)
#pragma unroll
      for (int k = 0; k < 8; ++k) { s[k] += ls[cg + 32 * g][k]; q[k] += lq[cg + 32 * g][k]; }
#pragma unroll
    for (int k = 0; k < 8; ++k) {
      atomicAdd(&sums[cg * 8 + k], s[k]);
      atomicAdd(&sums[D + cg * 8 + k], q[k]);
    }
  }
}

// ---------------- Classifier (fused BN norm) --------------------------------
__global__ void k_classifier(const unsigned short* __restrict__ F, const float* __restrict__ W,
                             const float* __restrict__ sums, const float* __restrict__ cls_b,
                             float* __restrict__ out, int N, int baseRow, int writeMode)
{
  const int n = blockIdx.x * 8 + (threadIdx.x >> 5);
  if (n >= N) return;
  const int lane = threadIdx.x & 31;
  const int j0 = lane * 8;
  float mu[8], rs[8];
#pragma unroll
  for (int k = 0; k < 8; ++k) {
    const float m_ = sums[j0 + k] / (float)N;
    const float v_ = sums[D + j0 + k] / (float)N - m_ * m_;
    mu[k] = m_;
    rs[k] = rsqrtf(v_ + BN_EPS);
  }
  const uint4 f = *(const uint4*)(F + (size_t)n * D + j0);
  const unsigned w[4] = {f.x, f.y, f.z, f.w};
  float fv[8];
#pragma unroll
  for (int k = 0; k < 4; ++k) {
    fv[2 * k]     = (bf2f((unsigned short)(w[k] & 0xffff)) - mu[2 * k])     * rs[2 * k];
    fv[2 * k + 1] = (bf2f((unsigned short)(w[k] >> 16))    - mu[2 * k + 1]) * rs[2 * k + 1];
  }
  const float* Wr = W + (size_t)(baseRow + j0) * NCLS;
  float p[NCLS];
#pragma unroll
  for (int c = 0; c < NCLS; ++c) {
    float s = 0.f;
#pragma unroll
    for (int k = 0; k < 8; ++k) s = fmaf(fv[k], Wr[k * NCLS + c], s);
    p[c] = s;
  }
#pragma unroll
  for (int m = 1; m < 32; m <<= 1)
#pragma unroll
    for (int c = 0; c < NCLS; ++c) p[c] += __shfl_xor(p[c], m);
  if (lane == 0) {
    float* o = out + (size_t)n * NCLS;
    if (writeMode) {
#pragma unroll
      for (int c = 0; c < NCLS; ++c) o[c] = cls_b[c] + p[c];
    } else {
#pragma unroll
      for (int c = 0; c < NCLS; ++c) o[c] += p[c];
    }
  }
}

// ---------------------------------------------------------------------------
extern "C" void kernel_launch(void* const* d_in, const int* in_sizes, int n_in,
                              void* d_out, int out_size, void* d_ws, size_t ws_size,
                              hipStream_t stream)
{
  const float* f_in   = (const float*)d_in[0];
  const int*   erow   = (const int*)d_in[1];
  const int*   ecol   = (const int*)d_in[2];
  const float* eval   = (const float*)d_in[3];
  const float* gat_Ws = (const float*)d_in[4];
  const float* gat_bs = (const float*)d_in[5];
  const float* gat_Wn = (const float*)d_in[6];
  const float* gat_bn = (const float*)d_in[7];
  const float* gat_as = (const float*)d_in[8];
  const float* gat_an = (const float*)d_in[9];
  const float* gcn_W  = (const float*)d_in[10];
  const float* gcn_b  = (const float*)d_in[11];
  const float* self_W = (const float*)d_in[12];
  const float* self_b = (const float*)d_in[13];
  const float* cls_W  = (const float*)d_in[14];
  const float* cls_b  = (const float*)d_in[15];
  float* out = (float*)d_out;

  const int N  = in_sizes[0] / D;      // 50000
  const int E  = in_sizes[1] / 4;      // 400000
  const int E4 = 4 * E, N4 = 4 * N;
  const size_t ND = (size_t)N * D;
  const size_t WM = (size_t)D * D;
  const int buckets = N4 >> 3;         // 8-node buckets

  // ---- workspace carve-up ----
  unsigned short* F  = (unsigned short*)d_ws;    // f_in bf16; recycled later
  unsigned short* O0 = F + ND;                   // O0..O4 contiguous (GEMM slots)
  unsigned short* O1 = O0 + ND;
  unsigned short* O2 = O0 + 2 * ND;
  unsigned short* O3 = O0 + 3 * ND;
  unsigned short* O4 = O0 + 4 * ND;              // self out; Phase-A tmp aliases here
  float* attS   = (float*)(O0 + 5 * ND);
  float* attN   = attS + (size_t)N * NHEAD;
  unsigned short* Wt  = (unsigned short*)(attN + (size_t)N * NHEAD);  // 11*65536
  unsigned short* Wt2 = Wt + 11 * WM;            // 5*65536 (folded L1 weights)
  float* bias2  = (float*)(Wt2 + 5 * WM);        // 11*256
  float* bias3  = bias2 + 11 * D;                // 5*256 (folded biases)
  int*   blkSum = (int*)(bias3 + 5 * D);         // 1024
  int*   rowptr = blkSum + 1024;                 // N4+1 (+pad)
  int2*  edge   = (int2*)(rowptr + N4 + 4);      // E4 (final CSR records)
  float* bnsums = (float*)(edge + E4);           // 9*512  [zeroed]
  // aliases into the edge region (dead before Phase B writes edge):
  int*   cnt     = (int*)edge;                   // N4     [zeroed]
  int*   bfill   = cnt + N4;                     // buckets [zeroed]
  int*   scanTmp = bfill + buckets;              // N4
  int2*  tmp     = (int2*)O4;                    // E4 (dead before GEMM1 writes O4)

  const int nb8   = (N + 7) / 8;
  const int scanG = (N4 + 255) / 256;
  const int nx    = (N + 127) / 128;

  hipMemsetAsync(cnt, 0, ((size_t)N4 + buckets) * sizeof(int), stream);
  hipMemsetAsync(bnsums, 0, 9 * 2 * D * sizeof(float), stream);

  // conversions
  k_cvt  <<<(int)(ND / 8 + 255) / 256, 256, 0, stream>>>(f_in, F, (int)(ND / 8));
  k_cvt_w<<<11 * 256, 256, 0, stream>>>(gat_Ws, gat_Wn, gcn_W, self_W, Wt);
  k_cvt_b<<<11, 256, 0, stream>>>(gat_bs, gat_bn, gcn_b, self_b, bias2);

  // batched CSR (4 adjacencies), two-phase with 8-node buckets
  k_count   <<<(E4 + 255) / 256, 256, 0, stream>>>(erow, cnt, E4, E, N);
  k_scan_blk<<<scanG, 256, 0, stream>>>(cnt, scanTmp, blkSum, N4);
  k_scan_top<<<1, 1024, 0, stream>>>(blkSum, scanG);
  k_scan_fin<<<scanG, 256, 0, stream>>>(scanTmp, blkSum, rowptr, N4);
  k_phaseA  <<<(E4 + 255) / 256, 256, 0, stream>>>(erow, ecol, eval, rowptr, bfill,
                                                   tmp, E4, E, N);
  k_phaseB  <<<buckets, 64, 0, stream>>>(tmp, rowptr, edge, N4);

  const int* rp0 = rowptr;
  const int* rp1 = rowptr + N;
  const int* rp2 = rowptr + 2 * N;
  const int* rp3 = rowptr + 3 * N;
  float* sums = bnsums;   // slot i at sums + i*512

  Tri triF = {F, F, F};
  Tri triX = {F, O0, O4};

  // ---- mega GEMM 1: A=F(f_in), segs [att | Wn0 | g0 | g1 | g2 | self] ------
  k_gemm<<<dim3(nx * 12, 1, 1), 256, 0, stream>>>(
      triF, Wt, bias2, O0, N, 12, 1, 0x22u, gat_as, gat_an, attS, attN);

  // ---- self branch (frees O4 early) ---------------------------------------
  k_bn_stats  <<<256, 256, 0, stream>>>(O4, sums + 8 * 512, N);
  k_classifier<<<nb8, 256, 0, stream>>>(O4, cls_W, sums + 8 * 512, cls_b, out, N, 4 * D, 1);

  // ---- GAT branch ----------------------------------------------------------
  k_gat_agg <<<nb8, 256, 0, stream>>>(O0, attS, attN, rp0, edge, F, N);
  k_bn_stats<<<256, 256, 0, stream>>>(F, sums + 0 * 512, N);
  k_fold    <<<dim3(256, 2), 256, 0, stream>>>(Wt + 6 * WM, bias2 + 6 * D, bnsums,
                                               Wt2, bias3, 0, N);
  k_gemm<<<dim3(nx * 4, 1, 1), 256, 0, stream>>>(
      triF, Wt2, bias3, O0, N, 4, 1, 0x02u, gat_as + D, gat_an + D, attS, attN);
  k_gat_agg <<<nb8, 256, 0, stream>>>(O0, attS, attN, rp0, edge, F, N);
  k_bn_stats<<<256, 256, 0, stream>>>(F, sums + 1 * 512, N);
  k_classifier<<<nb8, 256, 0, stream>>>(F, cls_W, sums + 1 * 512, cls_b, out, N, 0, 0);

  // ---- 3 GCN branches ------------------------------------------------------
  k_gcn_agg <<<nb8, 256, 0, stream>>>(O1, rp1, edge, F,  N);
  k_gcn_agg <<<nb8, 256, 0, stream>>>(O2, rp2, edge, O0, N);
  k_gcn_agg <<<nb8, 256, 0, stream>>>(O3, rp3, edge, O4, N);
  k_bn_stats<<<256, 256, 0, stream>>>(F,  sums + 2 * 512, N);
  k_bn_stats<<<256, 256, 0, stream>>>(O0, sums + 4 * 512, N);
  k_bn_stats<<<256, 256, 0, stream>>>(O4, sums + 6 * 512, N);
  k_fold    <<<dim3(256, 3), 256, 0, stream>>>(Wt + 6 * WM, bias2 + 6 * D, bnsums,
                                               Wt2, bias3, 2, N);
  k_gemm<<<dim3(nx * 2, 1, 3), 256, 0, stream>>>(
      triX, Wt2 + 2 * WM, bias3 + 2 * D, O1, N, 2, 0, 0x0u,
      nullptr, nullptr, nullptr, nullptr);
  k_gcn_agg <<<nb8, 256, 0, stream>>>(O1, rp1, edge, F,  N);
  k_gcn_agg <<<nb8, 256, 0, stream>>>(O2, rp2, edge, O0, N);
  k_gcn_agg <<<nb8, 256, 0, stream>>>(O3, rp3, edge, O4, N);
  k_bn_stats<<<256, 256, 0, stream>>>(F,  sums + 3 * 512, N);
  k_bn_stats<<<256, 256, 0, stream>>>(O0, sums + 5 * 512, N);
  k_bn_stats<<<256, 256, 0, stream>>>(O4, sums + 7 * 512, N);
  k_classifier<<<nb8, 256, 0, stream>>>(F,  cls_W, sums + 3 * 512, cls_b, out, N, 1 * D, 0);
  k_classifier<<<nb8, 256, 0, stream>>>(O0, cls_W, sums + 5 * 512, cls_b, out, N, 2 * D, 0);
  k_classifier<<<nb8, 256, 0, stream>>>(O4, cls_W, sums + 7 * 512, cls_b, out, N, 3 * D, 0);
}